// Round 1
// baseline (1240.923 us; speedup 1.0000x reference)
//
#include <hip/hip_runtime.h>
#include <hip/hip_bf16.h>

#define LRELU_SLOPE 0.2f

// ---------------- CSR build ----------------

__global__ void k_count(const int* __restrict__ ei, int* __restrict__ cnt, int E, int N) {
    int e = blockIdx.x * blockDim.x + threadIdx.x;
    if (e >= E + N) return;
    int dst = (e < E) ? ei[E + e] : (e - E);
    atomicAdd(&cnt[dst], 1);
}

// single-block exclusive scan of cnt[0..N) -> offs[0..N]
__global__ void k_scan(const int* __restrict__ cnt, int* __restrict__ offs, int N) {
    __shared__ int temp[1024];
    __shared__ int carry_s;
    int t = threadIdx.x;
    if (t == 0) carry_s = 0;
    __syncthreads();
    for (int base = 0; base < N; base += 1024) {
        int v = (base + t < N) ? cnt[base + t] : 0;
        temp[t] = v;
        __syncthreads();
        for (int o = 1; o < 1024; o <<= 1) {
            int x = (t >= o) ? temp[t - o] : 0;
            __syncthreads();
            temp[t] += x;
            __syncthreads();
        }
        int incl = temp[t];
        int carry = carry_s;
        if (base + t < N) offs[base + t] = carry + incl - v;
        __syncthreads();
        if (t == 1023) carry_s = carry + temp[1023];
        __syncthreads();
    }
    if (t == 0) offs[N] = carry_s;
}

__global__ void k_copy(const int* __restrict__ a, int* __restrict__ b, int N) {
    int i = blockIdx.x * blockDim.x + threadIdx.x;
    if (i < N) b[i] = a[i];
}

__global__ void k_scatter(const int* __restrict__ ei, int* __restrict__ wp,
                          int* __restrict__ adj, int E, int N) {
    int e = blockIdx.x * blockDim.x + threadIdx.x;
    if (e >= E + N) return;
    int srcn = (e < E) ? ei[e] : (e - E);
    int dst  = (e < E) ? ei[E + e] : (e - E);
    int pos = atomicAdd(&wp[dst], 1);
    adj[pos] = srcn;
}

// ---------------- GEMM: C[M,Nc] = A[M,K] * B[K,Nc], fp32 row-major ----------------
// block (16,16), tile 64x64, per-thread 4x4, K-slab 16.

__global__ void k_gemm(const float* __restrict__ A, const float* __restrict__ B,
                       float* __restrict__ C, int M, int Nc, int K) {
    __shared__ float As[16][64];  // [k][m]
    __shared__ float Bs[16][64];  // [k][n]
    int tx = threadIdx.x, ty = threadIdx.y;
    int tid = ty * 16 + tx;
    int bm = blockIdx.y * 64, bn = blockIdx.x * 64;

    float acc[4][4];
#pragma unroll
    for (int i = 0; i < 4; ++i)
#pragma unroll
        for (int j = 0; j < 4; ++j) acc[i][j] = 0.f;

    for (int k0 = 0; k0 < K; k0 += 16) {
#pragma unroll
        for (int i = 0; i < 4; ++i) {
            int idx = tid + i * 256;           // 0..1023
            int r = idx >> 4, kk = idx & 15;   // 64 rows x 16 k
            float v = 0.f;
            if (bm + r < M && k0 + kk < K) v = A[(long)(bm + r) * K + k0 + kk];
            As[kk][r] = v;
        }
#pragma unroll
        for (int i = 0; i < 4; ++i) {
            int idx = tid + i * 256;
            int kk = idx >> 6, c = idx & 63;   // 16 k x 64 n
            float v = 0.f;
            if (k0 + kk < K && bn + c < Nc) v = B[(long)(k0 + kk) * Nc + bn + c];
            Bs[kk][c] = v;
        }
        __syncthreads();
#pragma unroll
        for (int kk = 0; kk < 16; ++kk) {
            float a[4], b[4];
#pragma unroll
            for (int i = 0; i < 4; ++i) a[i] = As[kk][ty + i * 16];
#pragma unroll
            for (int j = 0; j < 4; ++j) b[j] = Bs[kk][tx + j * 16];
#pragma unroll
            for (int i = 0; i < 4; ++i)
#pragma unroll
                for (int j = 0; j < 4; ++j) acc[i][j] += a[i] * b[j];
        }
        __syncthreads();
    }

#pragma unroll
    for (int i = 0; i < 4; ++i) {
        int row = bm + ty + i * 16;
        if (row >= M) continue;
#pragma unroll
        for (int j = 0; j < 4; ++j) {
            int col = bn + tx + j * 16;
            if (col < Nc) C[(long)row * Nc + col] = acc[i][j];
        }
    }
}

// ---------------- per-(node,head) attention scores ----------------

__global__ void k_sd(const float* __restrict__ h, const float* __restrict__ a_src,
                     const float* __restrict__ a_dst, float* __restrict__ s,
                     float* __restrict__ d, int N, int H, int C) {
    int idx = blockIdx.x * blockDim.x + threadIdx.x;
    if (idx >= N * H) return;
    int hh = idx % H;
    long base = (long)idx * C;
    float ss = 0.f, dd = 0.f;
    for (int c = 0; c < C; ++c) {
        float v = h[base + c];
        ss += v * a_src[hh * C + c];
        dd += v * a_dst[hh * C + c];
    }
    s[idx] = ss;
    d[idx] = dd;
}

// ---------------- gather / segment-softmax / aggregate ----------------
// one thread per (dst node, head, channel); two passes over in-edges.

__global__ void k_gather(const float* __restrict__ h, const float* __restrict__ s,
                         const float* __restrict__ dsc, const int* __restrict__ offs,
                         const int* __restrict__ adj, const float* __restrict__ bias,
                         float* __restrict__ out, int N, int H, int C, int act) {
    long tid = (long)blockIdx.x * blockDim.x + threadIdx.x;
    int HC = H * C;
    if (tid >= (long)N * HC) return;
    int c  = (int)(tid % C);
    int hh = (int)((tid / C) % H);
    int n  = (int)(tid / HC);
    int beg = offs[n], end = offs[n + 1];
    float dn = dsc[n * H + hh];

    float m = -1e30f;
    for (int j = beg; j < end; ++j) {
        int sn = adj[j];
        float e = s[sn * H + hh] + dn;
        e = e > 0.f ? e : LRELU_SLOPE * e;
        m = fmaxf(m, e);
    }
    float denom = 0.f, acc = 0.f;
    for (int j = beg; j < end; ++j) {
        int sn = adj[j];
        float e = s[sn * H + hh] + dn;
        e = e > 0.f ? e : LRELU_SLOPE * e;
        float w = expf(e - m);
        denom += w;
        acc += w * h[(long)sn * HC + hh * C + c];
    }
    float o = acc / denom + bias[hh * C + c];
    if (act == 1) o = o > 0.f ? o : (expf(o) - 1.f);  // elu
    out[tid] = o;
}

// ---------------- final log_softmax over C channels ----------------

__global__ void k_lsm(const float* __restrict__ in, float* __restrict__ out, int N, int C) {
    int n = blockIdx.x * blockDim.x + threadIdx.x;
    if (n >= N) return;
    long base = (long)n * C;
    float m = -1e30f;
    for (int c = 0; c < C; ++c) m = fmaxf(m, in[base + c]);
    float ssum = 0.f;
    for (int c = 0; c < C; ++c) ssum += expf(in[base + c] - m);
    float lse = m + logf(ssum);
    for (int c = 0; c < C; ++c) out[base + c] = in[base + c] - lse;
}

// ---------------- host ----------------

static inline size_t align_up(size_t x) { return (x + 255) & ~(size_t)255; }

extern "C" void kernel_launch(void* const* d_in, const int* in_sizes, int n_in,
                              void* d_out, int out_size, void* d_ws, size_t ws_size,
                              hipStream_t stream) {
    const float* x   = (const float*)d_in[0];
    const int*   ei  = (const int*)d_in[1];
    const float* W1  = (const float*)d_in[2];
    const float* as1 = (const float*)d_in[3];
    const float* ad1 = (const float*)d_in[4];
    const float* b1  = (const float*)d_in[5];
    const float* W2  = (const float*)d_in[6];
    const float* as2 = (const float*)d_in[7];
    const float* ad2 = (const float*)d_in[8];
    const float* b2  = (const float*)d_in[9];
    const float* W3  = (const float*)d_in[10];
    const float* as3 = (const float*)d_in[11];
    const float* ad3 = (const float*)d_in[12];
    const float* b3  = (const float*)d_in[13];
    const float* W4  = (const float*)d_in[14];
    const float* as4 = (const float*)d_in[15];
    const float* ad4 = (const float*)d_in[16];
    const float* b4  = (const float*)d_in[17];

    const int N = in_sizes[0] / 256;   // 50000
    const int E = in_sizes[1] / 2;     // 400000
    const int ET = E + N;              // edges incl. self-loops

    // workspace layout
    size_t off = 0;
    char* ws = (char*)d_ws;
    auto take = [&](size_t bytes) { char* p = ws + off; off += align_up(bytes); return p; };
    int*   offs = (int*)take((size_t)(N + 1) * 4);
    int*   wp   = (int*)take((size_t)N * 4);
    int*   adj  = (int*)take((size_t)ET * 4);
    float* sbuf = (float*)take((size_t)N * 8 * 4);
    float* dbuf = (float*)take((size_t)N * 8 * 4);
    float* bufA = (float*)take((size_t)N * 256 * 4);
    float* bufB = (float*)take((size_t)N * 256 * 4);
    (void)ws_size;

    // ---- CSR build ----
    hipMemsetAsync(wp, 0, (size_t)N * 4, stream);
    {
        int nb = (ET + 255) / 256;
        k_count<<<nb, 256, 0, stream>>>(ei, wp, E, N);
        k_scan<<<1, 1024, 0, stream>>>(wp, offs, N);
        k_copy<<<(N + 255) / 256, 256, 0, stream>>>(offs, wp, N);
        k_scatter<<<nb, 256, 0, stream>>>(ei, wp, adj, E, N);
    }

    struct Layer { const float* W; const float* as; const float* ad; const float* b;
                   int Fin; int H; int C; };
    Layer layers[4] = {
        {W1, as1, ad1, b1, 256, 8, 32},
        {W2, as2, ad2, b2, 256, 4, 32},
        {W3, as3, ad3, b3, 128, 2, 32},
        {W4, as4, ad4, b4,  64, 1, 32},
    };

    const float* cur_x = x;
    for (int li = 0; li < 4; ++li) {
        Layer& L = layers[li];
        int HC = L.H * L.C;
        // GEMM: bufA[N,HC] = cur_x[N,Fin] @ W[Fin,HC]
        {
            dim3 blk(16, 16);
            dim3 grd((HC + 63) / 64, (N + 63) / 64);
            k_gemm<<<grd, blk, 0, stream>>>(cur_x, L.W, bufA, N, HC, L.Fin);
        }
        // scores
        {
            int nb = (N * L.H + 255) / 256;
            k_sd<<<nb, 256, 0, stream>>>(bufA, L.as, L.ad, sbuf, dbuf, N, L.H, L.C);
        }
        // gather + softmax-aggregate (+bias, +elu for layers 0..2)
        {
            long total = (long)N * HC;
            int nb = (int)((total + 255) / 256);
            int act = (li < 3) ? 1 : 0;
            k_gather<<<nb, 256, 0, stream>>>(bufA, sbuf, dbuf, offs, adj, L.b, bufB,
                                             N, L.H, L.C, act);
        }
        cur_x = bufB;
        // swap ping-pong: next GEMM writes bufA again (reads bufB) — already arranged
        float* t = bufA; bufA = bufB; bufB = t;
        cur_x = bufB;  // after swap, the layer output is in bufB's old (now bufB) slot
        // NOTE: after swap, output buffer is what bufB pointed to before? Keep explicit:
        // Simpler: cur_x points at the gather output, which is the pre-swap bufB == post-swap bufA.
        cur_x = bufA;
    }

    // cur_x now points at layer-4 output [N,32] (pre log-softmax)
    k_lsm<<<(N + 255) / 256, 256, 0, stream>>>(cur_x, (float*)d_out, N, 32);
}

// Round 2
// 877.242 us; speedup vs baseline: 1.4146x; 1.4146x over previous
//
#include <hip/hip_runtime.h>
#include <hip/hip_bf16.h>

#define LRELU_SLOPE 0.2f

// ---------------- CSR build ----------------

__global__ void k_count(const int* __restrict__ ei, int* __restrict__ cnt, int E, int N) {
    int e = blockIdx.x * blockDim.x + threadIdx.x;
    if (e >= E + N) return;
    int dst = (e < E) ? ei[E + e] : (e - E);
    atomicAdd(&cnt[dst], 1);
}

// single-block exclusive scan of cnt[0..N) -> offs[0..N]
__global__ void k_scan(const int* __restrict__ cnt, int* __restrict__ offs, int N) {
    __shared__ int temp[1024];
    __shared__ int carry_s;
    int t = threadIdx.x;
    if (t == 0) carry_s = 0;
    __syncthreads();
    for (int base = 0; base < N; base += 1024) {
        int v = (base + t < N) ? cnt[base + t] : 0;
        temp[t] = v;
        __syncthreads();
        for (int o = 1; o < 1024; o <<= 1) {
            int x = (t >= o) ? temp[t - o] : 0;
            __syncthreads();
            temp[t] += x;
            __syncthreads();
        }
        int incl = temp[t];
        int carry = carry_s;
        if (base + t < N) offs[base + t] = carry + incl - v;
        __syncthreads();
        if (t == 1023) carry_s = carry + temp[1023];
        __syncthreads();
    }
    if (t == 0) offs[N] = carry_s;
}

__global__ void k_copy(const int* __restrict__ a, int* __restrict__ b, int N) {
    int i = blockIdx.x * blockDim.x + threadIdx.x;
    if (i < N) b[i] = a[i];
}

__global__ void k_scatter(const int* __restrict__ ei, int* __restrict__ wp,
                          int* __restrict__ adj, int E, int N) {
    int e = blockIdx.x * blockDim.x + threadIdx.x;
    if (e >= E + N) return;
    int srcn = (e < E) ? ei[e] : (e - E);
    int dst  = (e < E) ? ei[E + e] : (e - E);
    int pos = atomicAdd(&wp[dst], 1);
    adj[pos] = srcn;
}

// ---------------- GEMM: C[M,Nc] = A[M,K] * B[K,Nc], fp32 row-major ----------------

__global__ void k_gemm(const float* __restrict__ A, const float* __restrict__ B,
                       float* __restrict__ C, int M, int Nc, int K) {
    __shared__ float As[16][64];  // [k][m]
    __shared__ float Bs[16][64];  // [k][n]
    int tx = threadIdx.x, ty = threadIdx.y;
    int tid = ty * 16 + tx;
    int bm = blockIdx.y * 64, bn = blockIdx.x * 64;

    float acc[4][4];
#pragma unroll
    for (int i = 0; i < 4; ++i)
#pragma unroll
        for (int j = 0; j < 4; ++j) acc[i][j] = 0.f;

    for (int k0 = 0; k0 < K; k0 += 16) {
#pragma unroll
        for (int i = 0; i < 4; ++i) {
            int idx = tid + i * 256;           // 0..1023
            int r = idx >> 4, kk = idx & 15;   // 64 rows x 16 k
            float v = 0.f;
            if (bm + r < M && k0 + kk < K) v = A[(long)(bm + r) * K + k0 + kk];
            As[kk][r] = v;
        }
#pragma unroll
        for (int i = 0; i < 4; ++i) {
            int idx = tid + i * 256;
            int kk = idx >> 6, c = idx & 63;   // 16 k x 64 n
            float v = 0.f;
            if (k0 + kk < K && bn + c < Nc) v = B[(long)(k0 + kk) * Nc + bn + c];
            Bs[kk][c] = v;
        }
        __syncthreads();
#pragma unroll
        for (int kk = 0; kk < 16; ++kk) {
            float a[4], b[4];
#pragma unroll
            for (int i = 0; i < 4; ++i) a[i] = As[kk][ty + i * 16];
#pragma unroll
            for (int j = 0; j < 4; ++j) b[j] = Bs[kk][tx + j * 16];
#pragma unroll
            for (int i = 0; i < 4; ++i)
#pragma unroll
                for (int j = 0; j < 4; ++j) acc[i][j] += a[i] * b[j];
        }
        __syncthreads();
    }

#pragma unroll
    for (int i = 0; i < 4; ++i) {
        int row = bm + ty + i * 16;
        if (row >= M) continue;
#pragma unroll
        for (int j = 0; j < 4; ++j) {
            int col = bn + tx + j * 16;
            if (col < Nc) C[(long)row * Nc + col] = acc[i][j];
        }
    }
}

// ---------------- per-(node,head) attention scores (float4) ----------------

__global__ void k_sd(const float* __restrict__ h, const float* __restrict__ a_src,
                     const float* __restrict__ a_dst, float* __restrict__ s,
                     float* __restrict__ d, int NH, int H, int C4) {
    int idx = blockIdx.x * blockDim.x + threadIdx.x;
    if (idx >= NH) return;
    int hh = idx % H;
    const float4* hp  = (const float4*)(h + (size_t)idx * C4 * 4);
    const float4* asp = (const float4*)(a_src + (size_t)hh * C4 * 4);
    const float4* adp = (const float4*)(a_dst + (size_t)hh * C4 * 4);
    float ss = 0.f, dd = 0.f;
    for (int c = 0; c < C4; ++c) {
        float4 hv = hp[c], av = asp[c], bv = adp[c];
        ss += hv.x * av.x + hv.y * av.y + hv.z * av.z + hv.w * av.w;
        dd += hv.x * bv.x + hv.y * bv.y + hv.z * bv.z + hv.w * bv.w;
    }
    s[idx] = ss;
    d[idx] = dd;
}

// ---------------- attention weights: one thread per (node, head) ----------------
// writes unnormalized w into per-head planes alpha[hh*ET + j], denom[n*H+hh]

__global__ void k_alpha(const float* __restrict__ s, const float* __restrict__ dsc,
                        const int* __restrict__ offs, const int* __restrict__ adj,
                        float* __restrict__ alpha, float* __restrict__ denom,
                        int NH, int H, int ET) {
    int idx = blockIdx.x * blockDim.x + threadIdx.x;
    if (idx >= NH) return;
    int hh = idx % H;
    int n  = idx / H;
    int beg = offs[n], end = offs[n + 1];
    float dn = dsc[idx];
    float m = -1e30f;
    for (int j = beg; j < end; ++j) {
        float e = s[adj[j] * H + hh] + dn;
        e = e > 0.f ? e : LRELU_SLOPE * e;
        m = fmaxf(m, e);
    }
    float dsum = 0.f;
    float* ap = alpha + (size_t)hh * ET;
    for (int j = beg; j < end; ++j) {
        float e = s[adj[j] * H + hh] + dn;
        e = e > 0.f ? e : LRELU_SLOPE * e;
        float w = expf(e - m);
        dsum += w;
        ap[j] = w;
    }
    denom[idx] = dsum;
}

// ---------------- aggregate: one thread per (node, head, c/4), single pass ----------------

__global__ void k_agg(const float* __restrict__ h, const float* __restrict__ alpha,
                      const float* __restrict__ denom, const int* __restrict__ offs,
                      const int* __restrict__ adj, const float* __restrict__ bias,
                      float* __restrict__ out, int N, int H, int C4, int ET, int act) {
    long tid = (long)blockIdx.x * blockDim.x + threadIdx.x;
    int HC4 = H * C4;
    if (tid >= (long)N * HC4) return;
    int c4 = (int)(tid % C4);
    int hh = (int)((tid / C4) % H);
    int n  = (int)(tid / HC4);
    int beg = offs[n], end = offs[n + 1];
    const float* ap = alpha + (size_t)hh * ET;
    int HC = HC4 * 4;
    float4 acc = {0.f, 0.f, 0.f, 0.f};
    for (int j = beg; j < end; ++j) {
        int sn = adj[j];
        float w = ap[j];
        float4 hv = *(const float4*)(h + (size_t)sn * HC + hh * C4 * 4 + c4 * 4);
        acc.x += w * hv.x; acc.y += w * hv.y; acc.z += w * hv.z; acc.w += w * hv.w;
    }
    float inv = 1.0f / denom[n * H + hh];
    float4 bv = *(const float4*)(bias + hh * C4 * 4 + c4 * 4);
    float4 o;
    o.x = acc.x * inv + bv.x;
    o.y = acc.y * inv + bv.y;
    o.z = acc.z * inv + bv.z;
    o.w = acc.w * inv + bv.w;
    if (act == 1) {
        o.x = o.x > 0.f ? o.x : (expf(o.x) - 1.f);
        o.y = o.y > 0.f ? o.y : (expf(o.y) - 1.f);
        o.z = o.z > 0.f ? o.z : (expf(o.z) - 1.f);
        o.w = o.w > 0.f ? o.w : (expf(o.w) - 1.f);
    }
    *(float4*)(out + tid * 4) = o;
}

// ---------------- fallback fused gather (used only if ws too small) ----------------

__global__ void k_gather(const float* __restrict__ h, const float* __restrict__ s,
                         const float* __restrict__ dsc, const int* __restrict__ offs,
                         const int* __restrict__ adj, const float* __restrict__ bias,
                         float* __restrict__ out, int N, int H, int C, int act) {
    long tid = (long)blockIdx.x * blockDim.x + threadIdx.x;
    int HC = H * C;
    if (tid >= (long)N * HC) return;
    int c  = (int)(tid % C);
    int hh = (int)((tid / C) % H);
    int n  = (int)(tid / HC);
    int beg = offs[n], end = offs[n + 1];
    float dn = dsc[n * H + hh];
    float m = -1e30f;
    for (int j = beg; j < end; ++j) {
        int sn = adj[j];
        float e = s[sn * H + hh] + dn;
        e = e > 0.f ? e : LRELU_SLOPE * e;
        m = fmaxf(m, e);
    }
    float denom = 0.f, acc = 0.f;
    for (int j = beg; j < end; ++j) {
        int sn = adj[j];
        float e = s[sn * H + hh] + dn;
        e = e > 0.f ? e : LRELU_SLOPE * e;
        float w = expf(e - m);
        denom += w;
        acc += w * h[(long)sn * HC + hh * C + c];
    }
    float o = acc / denom + bias[hh * C + c];
    if (act == 1) o = o > 0.f ? o : (expf(o) - 1.f);
    out[tid] = o;
}

// ---------------- final log_softmax over C channels ----------------

__global__ void k_lsm(const float* __restrict__ in, float* __restrict__ out, int N, int C) {
    int n = blockIdx.x * blockDim.x + threadIdx.x;
    if (n >= N) return;
    long base = (long)n * C;
    float m = -1e30f;
    for (int c = 0; c < C; ++c) m = fmaxf(m, in[base + c]);
    float ssum = 0.f;
    for (int c = 0; c < C; ++c) ssum += expf(in[base + c] - m);
    float lse = m + logf(ssum);
    for (int c = 0; c < C; ++c) out[base + c] = in[base + c] - lse;
}

// ---------------- host ----------------

static inline size_t align_up(size_t x) { return (x + 255) & ~(size_t)255; }

extern "C" void kernel_launch(void* const* d_in, const int* in_sizes, int n_in,
                              void* d_out, int out_size, void* d_ws, size_t ws_size,
                              hipStream_t stream) {
    const float* x   = (const float*)d_in[0];
    const int*   ei  = (const int*)d_in[1];

    const int N = in_sizes[0] / 256;   // 50000
    const int E = in_sizes[1] / 2;     // 400000
    const int ET = E + N;              // edges incl. self-loops

    // workspace layout
    size_t off = 0;
    char* ws = (char*)d_ws;
    auto take = [&](size_t bytes) { char* p = ws + off; off += align_up(bytes); return p; };
    int*   offs  = (int*)take((size_t)(N + 1) * 4);
    int*   wp    = (int*)take((size_t)N * 4);
    int*   adj   = (int*)take((size_t)ET * 4);
    float* sbuf  = (float*)take((size_t)N * 8 * 4);
    float* dbuf  = (float*)take((size_t)N * 8 * 4);
    float* dnbuf = (float*)take((size_t)N * 8 * 4);
    float* bufA  = (float*)take((size_t)N * 256 * 4);
    float* bufB  = (float*)take((size_t)N * 256 * 4);
    size_t alpha_need = (size_t)ET * 8 * 4;
    bool use_split = (off + align_up(alpha_need)) <= ws_size;
    float* alpha = use_split ? (float*)take(alpha_need) : nullptr;

    // ---- CSR build ----
    hipMemsetAsync(wp, 0, (size_t)N * 4, stream);
    {
        int nb = (ET + 255) / 256;
        k_count<<<nb, 256, 0, stream>>>(ei, wp, E, N);
        k_scan<<<1, 1024, 0, stream>>>(wp, offs, N);
        k_copy<<<(N + 255) / 256, 256, 0, stream>>>(offs, wp, N);
        k_scatter<<<nb, 256, 0, stream>>>(ei, wp, adj, E, N);
    }

    struct Layer { const float* W; const float* as; const float* ad; const float* b;
                   int Fin; int H; int C; };
    Layer layers[4] = {
        {(const float*)d_in[2],  (const float*)d_in[3],  (const float*)d_in[4],  (const float*)d_in[5],  256, 8, 32},
        {(const float*)d_in[6],  (const float*)d_in[7],  (const float*)d_in[8],  (const float*)d_in[9],  256, 4, 32},
        {(const float*)d_in[10], (const float*)d_in[11], (const float*)d_in[12], (const float*)d_in[13], 128, 2, 32},
        {(const float*)d_in[14], (const float*)d_in[15], (const float*)d_in[16], (const float*)d_in[17],  64, 1, 32},
    };

    const float* cur_x = x;
    float* hbuf = bufA;   // GEMM output
    float* obuf = bufB;   // layer output
    for (int li = 0; li < 4; ++li) {
        Layer& L = layers[li];
        int HC = L.H * L.C;
        int act = (li < 3) ? 1 : 0;
        // GEMM: hbuf[N,HC] = cur_x[N,Fin] @ W[Fin,HC]
        {
            dim3 blk(16, 16);
            dim3 grd((HC + 63) / 64, (N + 63) / 64);
            k_gemm<<<grd, blk, 0, stream>>>(cur_x, L.W, hbuf, N, HC, L.Fin);
        }
        // scores
        {
            int NH = N * L.H;
            int nb = (NH + 255) / 256;
            k_sd<<<nb, 256, 0, stream>>>(hbuf, L.as, L.ad, sbuf, dbuf, NH, L.H, L.C / 4);
        }
        if (use_split) {
            int NH = N * L.H;
            k_alpha<<<(NH + 255) / 256, 256, 0, stream>>>(sbuf, dbuf, offs, adj,
                                                          alpha, dnbuf, NH, L.H, ET);
            long total = (long)N * L.H * (L.C / 4);
            int nb = (int)((total + 255) / 256);
            k_agg<<<nb, 256, 0, stream>>>(hbuf, alpha, dnbuf, offs, adj, L.b, obuf,
                                          N, L.H, L.C / 4, ET, act);
        } else {
            long total = (long)N * HC;
            int nb = (int)((total + 255) / 256);
            k_gather<<<nb, 256, 0, stream>>>(hbuf, sbuf, dbuf, offs, adj, L.b, obuf,
                                             N, L.H, L.C, act);
        }
        cur_x = obuf;
        float* t = hbuf; hbuf = obuf; obuf = t;
    }

    // cur_x points at layer-4 output [N,32] (pre log-softmax)
    k_lsm<<<(N + 255) / 256, 256, 0, stream>>>(cur_x, (float*)d_out, N, 32);
}

// Round 3
// 646.191 us; speedup vs baseline: 1.9204x; 1.3576x over previous
//
#include <hip/hip_runtime.h>
#include <hip/hip_bf16.h>

#define LRELU_SLOPE 0.2f

typedef __attribute__((ext_vector_type(8))) short short8;
typedef __attribute__((ext_vector_type(4))) float f32x4;

__device__ __forceinline__ unsigned short bf16r(float f) {
    unsigned int u = __builtin_bit_cast(unsigned int, f);
    u += 0x7fffu + ((u >> 16) & 1u);   // RNE
    return (unsigned short)(u >> 16);
}

// ---------------- CSR build ----------------

__global__ void k_count(const int* __restrict__ ei, int* __restrict__ cnt, int E, int N) {
    int e = blockIdx.x * blockDim.x + threadIdx.x;
    if (e >= E + N) return;
    int dst = (e < E) ? ei[E + e] : (e - E);
    atomicAdd(&cnt[dst], 1);
}

__global__ void k_scan(const int* __restrict__ cnt, int* __restrict__ offs, int N) {
    __shared__ int temp[1024];
    __shared__ int carry_s;
    int t = threadIdx.x;
    if (t == 0) carry_s = 0;
    __syncthreads();
    for (int base = 0; base < N; base += 1024) {
        int v = (base + t < N) ? cnt[base + t] : 0;
        temp[t] = v;
        __syncthreads();
        for (int o = 1; o < 1024; o <<= 1) {
            int x = (t >= o) ? temp[t - o] : 0;
            __syncthreads();
            temp[t] += x;
            __syncthreads();
        }
        int incl = temp[t];
        int carry = carry_s;
        if (base + t < N) offs[base + t] = carry + incl - v;
        __syncthreads();
        if (t == 1023) carry_s = carry + temp[1023];
        __syncthreads();
    }
    if (t == 0) offs[N] = carry_s;
}

__global__ void k_copy(const int* __restrict__ a, int* __restrict__ b, int N) {
    int i = blockIdx.x * blockDim.x + threadIdx.x;
    if (i < N) b[i] = a[i];
}

__global__ void k_scatter(const int* __restrict__ ei, int* __restrict__ wp,
                          int* __restrict__ adj, int E, int N) {
    int e = blockIdx.x * blockDim.x + threadIdx.x;
    if (e >= E + N) return;
    int srcn = (e < E) ? ei[e] : (e - E);
    int dst  = (e < E) ? ei[E + e] : (e - E);
    int pos = atomicAdd(&wp[dst], 1);
    adj[pos] = srcn;
}

// ---------------- casts ----------------

__global__ void k_cast(const float* __restrict__ in, unsigned short* __restrict__ out, long n4) {
    long i = (long)blockIdx.x * blockDim.x + threadIdx.x;
    if (i >= n4) return;
    float4 v = ((const float4*)in)[i];
    ushort4 o;
    o.x = bf16r(v.x); o.y = bf16r(v.y); o.z = bf16r(v.z); o.w = bf16r(v.w);
    ((ushort4*)out)[i] = o;
}

// WT[n*K + k] = bf16(W[k*Nc + n])
__global__ void k_castWT(const float* __restrict__ W, unsigned short* __restrict__ WT,
                         int K, int Nc) {
    int id = blockIdx.x * blockDim.x + threadIdx.x;
    if (id >= K * Nc) return;
    int n = id / K, k = id % K;
    WT[id] = bf16r(W[(long)k * Nc + n]);
}

// ---------------- MFMA GEMM: C[M,Nc] = A[M,K](bf16) * WT[Nc,K](bf16)^T ----------------
// block 256 thr (4 waves), tile 128 rows x 64 cols; wave w: rows [32w,32w+32).
// K slab 32 per stage; per wave per stage: 2 A-frags, 4 B-frags, 8 MFMA.

#define PSTR 40  // padded LDS row stride in shorts (32 + 8 -> 2-way conflicts only)

__global__ __launch_bounds__(256) void k_mgemm(const unsigned short* __restrict__ A,
                                               const unsigned short* __restrict__ WT,
                                               float* __restrict__ C,
                                               int M, int Nc, int K) {
    __shared__ __align__(16) unsigned short As[128 * PSTR];
    __shared__ __align__(16) unsigned short Bs[64 * PSTR];
    int t = threadIdx.x;
    int wv = t >> 6, l = t & 63;
    int bm = blockIdx.y * 128, bn = blockIdx.x * 64;

    f32x4 acc[2][4];
#pragma unroll
    for (int i = 0; i < 2; ++i)
#pragma unroll
        for (int j = 0; j < 4; ++j) acc[i][j] = (f32x4){0.f, 0.f, 0.f, 0.f};

    // staging indices (16B chunks)
    int ar0 = t >> 2, akc0 = t & 3;           // A chunk 1: row, k-chunk
    int ar1 = (t + 256) >> 2, akc1 = t & 3;   // A chunk 2
    int bc0 = t >> 2, bkc0 = t & 3;           // B chunk
    int grA0 = min(bm + ar0, M - 1);
    int grA1 = min(bm + ar1, M - 1);
    int gcB0 = min(bn + bc0, Nc - 1);

    // frag LDS pointers (constant across K loop)
    int row_in = l & 15, quad = l >> 4;
    const short8* apf0 = (const short8*)&As[(wv * 32 + row_in) * PSTR + quad * 8];
    const short8* apf1 = (const short8*)&As[(wv * 32 + 16 + row_in) * PSTR + quad * 8];
    const short8* bpf0 = (const short8*)&Bs[(row_in) * PSTR + quad * 8];
    const short8* bpf1 = (const short8*)&Bs[(16 + row_in) * PSTR + quad * 8];
    const short8* bpf2 = (const short8*)&Bs[(32 + row_in) * PSTR + quad * 8];
    const short8* bpf3 = (const short8*)&Bs[(48 + row_in) * PSTR + quad * 8];

    for (int k0 = 0; k0 < K; k0 += 32) {
        // stage A (128x32) and B (64x32) into LDS, 16B chunks
        *(short8*)&As[ar0 * PSTR + akc0 * 8] =
            *(const short8*)&A[(long)grA0 * K + k0 + akc0 * 8];
        *(short8*)&As[ar1 * PSTR + akc1 * 8] =
            *(const short8*)&A[(long)grA1 * K + k0 + akc1 * 8];
        *(short8*)&Bs[bc0 * PSTR + bkc0 * 8] =
            *(const short8*)&WT[(long)gcB0 * K + k0 + bkc0 * 8];
        __syncthreads();

        short8 a0 = *apf0, a1 = *apf1;
        short8 b0 = *bpf0, b1 = *bpf1, b2 = *bpf2, b3 = *bpf3;
        acc[0][0] = __builtin_amdgcn_mfma_f32_16x16x32_bf16(a0, b0, acc[0][0], 0, 0, 0);
        acc[0][1] = __builtin_amdgcn_mfma_f32_16x16x32_bf16(a0, b1, acc[0][1], 0, 0, 0);
        acc[0][2] = __builtin_amdgcn_mfma_f32_16x16x32_bf16(a0, b2, acc[0][2], 0, 0, 0);
        acc[0][3] = __builtin_amdgcn_mfma_f32_16x16x32_bf16(a0, b3, acc[0][3], 0, 0, 0);
        acc[1][0] = __builtin_amdgcn_mfma_f32_16x16x32_bf16(a1, b0, acc[1][0], 0, 0, 0);
        acc[1][1] = __builtin_amdgcn_mfma_f32_16x16x32_bf16(a1, b1, acc[1][1], 0, 0, 0);
        acc[1][2] = __builtin_amdgcn_mfma_f32_16x16x32_bf16(a1, b2, acc[1][2], 0, 0, 0);
        acc[1][3] = __builtin_amdgcn_mfma_f32_16x16x32_bf16(a1, b3, acc[1][3], 0, 0, 0);
        __syncthreads();
    }

    // epilogue: C/D layout col=lane&15, row=quad*4+reg  (m89-verified)
#pragma unroll
    for (int rt = 0; rt < 2; ++rt) {
#pragma unroll
        for (int r = 0; r < 4; ++r) {
            int row = bm + wv * 32 + rt * 16 + quad * 4 + r;
            if (row >= M) continue;
#pragma unroll
            for (int ct = 0; ct < 4; ++ct) {
                int col = bn + ct * 16 + row_in;
                if (col < Nc) C[(long)row * Nc + col] = acc[rt][ct][r];
            }
        }
    }
}

// ---------------- per-(node,head) attention scores (float4) ----------------

__global__ void k_sd(const float* __restrict__ h, const float* __restrict__ a_src,
                     const float* __restrict__ a_dst, float* __restrict__ s,
                     float* __restrict__ d, int NH, int H, int C4) {
    int idx = blockIdx.x * blockDim.x + threadIdx.x;
    if (idx >= NH) return;
    int hh = idx % H;
    const float4* hp  = (const float4*)(h + (size_t)idx * C4 * 4);
    const float4* asp = (const float4*)(a_src + (size_t)hh * C4 * 4);
    const float4* adp = (const float4*)(a_dst + (size_t)hh * C4 * 4);
    float ss = 0.f, dd = 0.f;
    for (int c = 0; c < C4; ++c) {
        float4 hv = hp[c], av = asp[c], bv = adp[c];
        ss += hv.x * av.x + hv.y * av.y + hv.z * av.z + hv.w * av.w;
        dd += hv.x * bv.x + hv.y * bv.y + hv.z * bv.z + hv.w * bv.w;
    }
    s[idx] = ss;
    d[idx] = dd;
}

// ---------------- attention weights: one thread per (node, head) ----------------

__global__ void k_alpha(const float* __restrict__ s, const float* __restrict__ dsc,
                        const int* __restrict__ offs, const int* __restrict__ adj,
                        float* __restrict__ alpha, float* __restrict__ denom,
                        int NH, int H, int ET) {
    int idx = blockIdx.x * blockDim.x + threadIdx.x;
    if (idx >= NH) return;
    int hh = idx % H;
    int n  = idx / H;
    int beg = offs[n], end = offs[n + 1];
    float dn = dsc[idx];
    float m = -1e30f;
    for (int j = beg; j < end; ++j) {
        float e = s[adj[j] * H + hh] + dn;
        e = e > 0.f ? e : LRELU_SLOPE * e;
        m = fmaxf(m, e);
    }
    float dsum = 0.f;
    float* ap = alpha + (size_t)hh * ET;
    for (int j = beg; j < end; ++j) {
        float e = s[adj[j] * H + hh] + dn;
        e = e > 0.f ? e : LRELU_SLOPE * e;
        float w = expf(e - m);
        dsum += w;
        ap[j] = w;
    }
    denom[idx] = dsum;
}

// ---------------- aggregate: one thread per (node, head, c/4), single pass ----------------

__global__ void k_agg(const float* __restrict__ h, const float* __restrict__ alpha,
                      const float* __restrict__ denom, const int* __restrict__ offs,
                      const int* __restrict__ adj, const float* __restrict__ bias,
                      float* __restrict__ out, int N, int H, int C4, int ET, int act) {
    long tid = (long)blockIdx.x * blockDim.x + threadIdx.x;
    int HC4 = H * C4;
    if (tid >= (long)N * HC4) return;
    int c4 = (int)(tid % C4);
    int hh = (int)((tid / C4) % H);
    int n  = (int)(tid / HC4);
    int beg = offs[n], end = offs[n + 1];
    const float* ap = alpha + (size_t)hh * ET;
    int HC = HC4 * 4;
    float4 acc = {0.f, 0.f, 0.f, 0.f};
    for (int j = beg; j < end; ++j) {
        int sn = adj[j];
        float w = ap[j];
        float4 hv = *(const float4*)(h + (size_t)sn * HC + hh * C4 * 4 + c4 * 4);
        acc.x += w * hv.x; acc.y += w * hv.y; acc.z += w * hv.z; acc.w += w * hv.w;
    }
    float inv = 1.0f / denom[n * H + hh];
    float4 bv = *(const float4*)(bias + hh * C4 * 4 + c4 * 4);
    float4 o;
    o.x = acc.x * inv + bv.x;
    o.y = acc.y * inv + bv.y;
    o.z = acc.z * inv + bv.z;
    o.w = acc.w * inv + bv.w;
    if (act == 1) {
        o.x = o.x > 0.f ? o.x : (expf(o.x) - 1.f);
        o.y = o.y > 0.f ? o.y : (expf(o.y) - 1.f);
        o.z = o.z > 0.f ? o.z : (expf(o.z) - 1.f);
        o.w = o.w > 0.f ? o.w : (expf(o.w) - 1.f);
    }
    *(float4*)(out + tid * 4) = o;
}

// ---------------- fallback fused gather ----------------

__global__ void k_gather(const float* __restrict__ h, const float* __restrict__ s,
                         const float* __restrict__ dsc, const int* __restrict__ offs,
                         const int* __restrict__ adj, const float* __restrict__ bias,
                         float* __restrict__ out, int N, int H, int C, int act) {
    long tid = (long)blockIdx.x * blockDim.x + threadIdx.x;
    int HC = H * C;
    if (tid >= (long)N * HC) return;
    int c  = (int)(tid % C);
    int hh = (int)((tid / C) % H);
    int n  = (int)(tid / HC);
    int beg = offs[n], end = offs[n + 1];
    float dn = dsc[n * H + hh];
    float m = -1e30f;
    for (int j = beg; j < end; ++j) {
        int sn = adj[j];
        float e = s[sn * H + hh] + dn;
        e = e > 0.f ? e : LRELU_SLOPE * e;
        m = fmaxf(m, e);
    }
    float denom = 0.f, acc = 0.f;
    for (int j = beg; j < end; ++j) {
        int sn = adj[j];
        float e = s[sn * H + hh] + dn;
        e = e > 0.f ? e : LRELU_SLOPE * e;
        float w = expf(e - m);
        denom += w;
        acc += w * h[(long)sn * HC + hh * C + c];
    }
    float o = acc / denom + bias[hh * C + c];
    if (act == 1) o = o > 0.f ? o : (expf(o) - 1.f);
    out[tid] = o;
}

// ---------------- final log_softmax over C channels ----------------

__global__ void k_lsm(const float* __restrict__ in, float* __restrict__ out, int N, int C) {
    int n = blockIdx.x * blockDim.x + threadIdx.x;
    if (n >= N) return;
    long base = (long)n * C;
    float m = -1e30f;
    for (int c = 0; c < C; ++c) m = fmaxf(m, in[base + c]);
    float ssum = 0.f;
    for (int c = 0; c < C; ++c) ssum += expf(in[base + c] - m);
    float lse = m + logf(ssum);
    for (int c = 0; c < C; ++c) out[base + c] = in[base + c] - lse;
}

// ---------------- host ----------------

static inline size_t align_up(size_t x) { return (x + 255) & ~(size_t)255; }

extern "C" void kernel_launch(void* const* d_in, const int* in_sizes, int n_in,
                              void* d_out, int out_size, void* d_ws, size_t ws_size,
                              hipStream_t stream) {
    const float* x   = (const float*)d_in[0];
    const int*   ei  = (const int*)d_in[1];

    const int N = in_sizes[0] / 256;   // 50000
    const int E = in_sizes[1] / 2;     // 400000
    const int ET = E + N;

    size_t off = 0;
    char* ws = (char*)d_ws;
    auto take = [&](size_t bytes) { char* p = ws + off; off += align_up(bytes); return p; };
    int*   offs  = (int*)take((size_t)(N + 1) * 4);
    int*   wp    = (int*)take((size_t)N * 4);
    int*   adj   = (int*)take((size_t)ET * 4);
    float* sbuf  = (float*)take((size_t)N * 8 * 4);
    float* dbuf  = (float*)take((size_t)N * 8 * 4);
    float* dnbuf = (float*)take((size_t)N * 8 * 4);
    float* bufA  = (float*)take((size_t)N * 256 * 4);
    float* bufB  = (float*)take((size_t)N * 256 * 4);
    unsigned short* Abf = (unsigned short*)take((size_t)N * 256 * 2);
    unsigned short* WTb = (unsigned short*)take((size_t)256 * 256 * 2);
    size_t alpha_need = (size_t)ET * 8 * 4;
    bool use_split = (off + align_up(alpha_need)) <= ws_size;
    float* alpha = use_split ? (float*)take(alpha_need) : nullptr;

    // ---- CSR build ----
    hipMemsetAsync(wp, 0, (size_t)N * 4, stream);
    {
        int nb = (ET + 255) / 256;
        k_count<<<nb, 256, 0, stream>>>(ei, wp, E, N);
        k_scan<<<1, 1024, 0, stream>>>(wp, offs, N);
        k_copy<<<(N + 255) / 256, 256, 0, stream>>>(offs, wp, N);
        k_scatter<<<nb, 256, 0, stream>>>(ei, wp, adj, E, N);
    }

    struct Layer { const float* W; const float* as; const float* ad; const float* b;
                   int Fin; int H; int C; };
    Layer layers[4] = {
        {(const float*)d_in[2],  (const float*)d_in[3],  (const float*)d_in[4],  (const float*)d_in[5],  256, 8, 32},
        {(const float*)d_in[6],  (const float*)d_in[7],  (const float*)d_in[8],  (const float*)d_in[9],  256, 4, 32},
        {(const float*)d_in[10], (const float*)d_in[11], (const float*)d_in[12], (const float*)d_in[13], 128, 2, 32},
        {(const float*)d_in[14], (const float*)d_in[15], (const float*)d_in[16], (const float*)d_in[17],  64, 1, 32},
    };

    const float* cur_x = x;
    float* hbuf = bufA;
    float* obuf = bufB;
    for (int li = 0; li < 4; ++li) {
        Layer& L = layers[li];
        int HC = L.H * L.C;
        int K = L.Fin;
        int act = (li < 3) ? 1 : 0;

        // cast A (activations) to bf16
        {
            long n4 = (long)N * K / 4;
            int nb = (int)((n4 + 255) / 256);
            k_cast<<<nb, 256, 0, stream>>>(cur_x, Abf, n4);
        }
        // cast+transpose W -> WT[Nc][K]
        {
            int tot = K * HC;
            k_castWT<<<(tot + 255) / 256, 256, 0, stream>>>(L.W, WTb, K, HC);
        }
        // MFMA GEMM: hbuf[N,HC] = Abf[N,K] @ WT^T
        {
            dim3 grd((HC + 63) / 64, (N + 127) / 128);
            k_mgemm<<<grd, 256, 0, stream>>>(Abf, WTb, hbuf, N, HC, K);
        }
        // scores
        {
            int NH = N * L.H;
            k_sd<<<(NH + 255) / 256, 256, 0, stream>>>(hbuf, L.as, L.ad, sbuf, dbuf,
                                                       NH, L.H, L.C / 4);
        }
        if (use_split) {
            int NH = N * L.H;
            k_alpha<<<(NH + 255) / 256, 256, 0, stream>>>(sbuf, dbuf, offs, adj,
                                                          alpha, dnbuf, NH, L.H, ET);
            long total = (long)N * L.H * (L.C / 4);
            int nb = (int)((total + 255) / 256);
            k_agg<<<nb, 256, 0, stream>>>(hbuf, alpha, dnbuf, offs, adj, L.b, obuf,
                                          N, L.H, L.C / 4, ET, act);
        } else {
            long total = (long)N * HC;
            int nb = (int)((total + 255) / 256);
            k_gather<<<nb, 256, 0, stream>>>(hbuf, sbuf, dbuf, offs, adj, L.b, obuf,
                                             N, L.H, L.C, act);
        }
        cur_x = obuf;
        float* t = hbuf; hbuf = obuf; obuf = t;
    }

    k_lsm<<<(N + 255) / 256, 256, 0, stream>>>(cur_x, (float*)d_out, N, 32);
}

// Round 4
// 563.871 us; speedup vs baseline: 2.2007x; 1.1460x over previous
//
#include <hip/hip_runtime.h>
#include <hip/hip_bf16.h>

#define LRELU_SLOPE 0.2f

typedef __attribute__((ext_vector_type(8))) short short8;
typedef __attribute__((ext_vector_type(4))) float f32x4;

__device__ __forceinline__ unsigned short bf16r(float f) {
    unsigned int u = __builtin_bit_cast(unsigned int, f);
    u += 0x7fffu + ((u >> 16) & 1u);   // RNE
    return (unsigned short)(u >> 16);
}

// ---------------- CSR build ----------------

__global__ void k_count(const int* __restrict__ ei, int* __restrict__ cnt, int E, int N) {
    int e = blockIdx.x * blockDim.x + threadIdx.x;
    if (e >= E + N) return;
    int dst = (e < E) ? ei[E + e] : (e - E);
    atomicAdd(&cnt[dst], 1);
}

// level-0: each block scans its 1024-chunk; writes block-local EXCLUSIVE scan
// into offs[gi] and the block total into bsum[blockIdx].
__global__ void k_scan_blk(const int* __restrict__ cnt, int* __restrict__ offs,
                           int* __restrict__ bsum, int N) {
    __shared__ int temp[1024];
    int t = threadIdx.x;
    int gi = blockIdx.x * 1024 + t;
    int v = (gi < N) ? cnt[gi] : 0;
    temp[t] = v;
    __syncthreads();
    for (int o = 1; o < 1024; o <<= 1) {
        int x = (t >= o) ? temp[t - o] : 0;
        __syncthreads();
        temp[t] += x;
        __syncthreads();
    }
    if (gi < N) offs[gi] = temp[t] - v;
    if (t == 1023) bsum[blockIdx.x] = temp[1023];
}

// generic single-block scan (used for the tiny top level, nb<=1024 -> 1 iter)
__global__ void k_scan(const int* __restrict__ cnt, int* __restrict__ offs, int N) {
    __shared__ int temp[1024];
    __shared__ int carry_s;
    int t = threadIdx.x;
    if (t == 0) carry_s = 0;
    __syncthreads();
    for (int base = 0; base < N; base += 1024) {
        int v = (base + t < N) ? cnt[base + t] : 0;
        temp[t] = v;
        __syncthreads();
        for (int o = 1; o < 1024; o <<= 1) {
            int x = (t >= o) ? temp[t - o] : 0;
            __syncthreads();
            temp[t] += x;
            __syncthreads();
        }
        int incl = temp[t];
        int carry = carry_s;
        if (base + t < N) offs[base + t] = carry + incl - v;
        __syncthreads();
        if (t == 1023) carry_s = carry + temp[1023];
        __syncthreads();
    }
    if (t == 0) offs[N] = carry_s;
}

// level-2: add block prefix; write both offs and the scatter cursors wp.
__global__ void k_scan_add(int* __restrict__ offs, const int* __restrict__ bpre,
                           int* __restrict__ wp, int N, int nb) {
    int gi = blockIdx.x * blockDim.x + threadIdx.x;
    if (gi < N) {
        int v = offs[gi] + bpre[gi >> 10];
        offs[gi] = v;
        wp[gi] = v;
    } else if (gi == N) {
        offs[N] = bpre[nb];
    }
}

__global__ void k_scatter(const int* __restrict__ ei, int* __restrict__ wp,
                          int* __restrict__ adj, int E, int N) {
    int e = blockIdx.x * blockDim.x + threadIdx.x;
    if (e >= E + N) return;
    int srcn = (e < E) ? ei[e] : (e - E);
    int dst  = (e < E) ? ei[E + e] : (e - E);
    int pos = atomicAdd(&wp[dst], 1);
    adj[pos] = srcn;
}

// ---------------- casts ----------------

__global__ void k_cast(const float* __restrict__ in, unsigned short* __restrict__ out, long n4) {
    long i = (long)blockIdx.x * blockDim.x + threadIdx.x;
    if (i >= n4) return;
    float4 v = ((const float4*)in)[i];
    ushort4 o;
    o.x = bf16r(v.x); o.y = bf16r(v.y); o.z = bf16r(v.z); o.w = bf16r(v.w);
    ((ushort4*)out)[i] = o;
}

// WT[n*K + k] = bf16(W[k*Nc + n])
__global__ void k_castWT(const float* __restrict__ W, unsigned short* __restrict__ WT,
                         int K, int Nc) {
    int id = blockIdx.x * blockDim.x + threadIdx.x;
    if (id >= K * Nc) return;
    int n = id / K, k = id % K;
    WT[id] = bf16r(W[(long)k * Nc + n]);
}

// ---------------- MFMA GEMM: C[M,Nc] = A[M,K](bf16) * WT[Nc,K](bf16)^T ----------------

#define PSTR 40  // padded LDS row stride in shorts

__global__ __launch_bounds__(256) void k_mgemm(const unsigned short* __restrict__ A,
                                               const unsigned short* __restrict__ WT,
                                               float* __restrict__ C,
                                               int M, int Nc, int K) {
    __shared__ __align__(16) unsigned short As[128 * PSTR];
    __shared__ __align__(16) unsigned short Bs[64 * PSTR];
    int t = threadIdx.x;
    int wv = t >> 6, l = t & 63;
    int bm = blockIdx.y * 128, bn = blockIdx.x * 64;

    f32x4 acc[2][4];
#pragma unroll
    for (int i = 0; i < 2; ++i)
#pragma unroll
        for (int j = 0; j < 4; ++j) acc[i][j] = (f32x4){0.f, 0.f, 0.f, 0.f};

    int ar0 = t >> 2, akc0 = t & 3;
    int ar1 = (t + 256) >> 2, akc1 = t & 3;
    int bc0 = t >> 2, bkc0 = t & 3;
    int grA0 = min(bm + ar0, M - 1);
    int grA1 = min(bm + ar1, M - 1);
    int gcB0 = min(bn + bc0, Nc - 1);

    int row_in = l & 15, quad = l >> 4;
    const short8* apf0 = (const short8*)&As[(wv * 32 + row_in) * PSTR + quad * 8];
    const short8* apf1 = (const short8*)&As[(wv * 32 + 16 + row_in) * PSTR + quad * 8];
    const short8* bpf0 = (const short8*)&Bs[(row_in) * PSTR + quad * 8];
    const short8* bpf1 = (const short8*)&Bs[(16 + row_in) * PSTR + quad * 8];
    const short8* bpf2 = (const short8*)&Bs[(32 + row_in) * PSTR + quad * 8];
    const short8* bpf3 = (const short8*)&Bs[(48 + row_in) * PSTR + quad * 8];

    for (int k0 = 0; k0 < K; k0 += 32) {
        *(short8*)&As[ar0 * PSTR + akc0 * 8] =
            *(const short8*)&A[(long)grA0 * K + k0 + akc0 * 8];
        *(short8*)&As[ar1 * PSTR + akc1 * 8] =
            *(const short8*)&A[(long)grA1 * K + k0 + akc1 * 8];
        *(short8*)&Bs[bc0 * PSTR + bkc0 * 8] =
            *(const short8*)&WT[(long)gcB0 * K + k0 + bkc0 * 8];
        __syncthreads();

        short8 a0 = *apf0, a1 = *apf1;
        short8 b0 = *bpf0, b1 = *bpf1, b2 = *bpf2, b3 = *bpf3;
        acc[0][0] = __builtin_amdgcn_mfma_f32_16x16x32_bf16(a0, b0, acc[0][0], 0, 0, 0);
        acc[0][1] = __builtin_amdgcn_mfma_f32_16x16x32_bf16(a0, b1, acc[0][1], 0, 0, 0);
        acc[0][2] = __builtin_amdgcn_mfma_f32_16x16x32_bf16(a0, b2, acc[0][2], 0, 0, 0);
        acc[0][3] = __builtin_amdgcn_mfma_f32_16x16x32_bf16(a0, b3, acc[0][3], 0, 0, 0);
        acc[1][0] = __builtin_amdgcn_mfma_f32_16x16x32_bf16(a1, b0, acc[1][0], 0, 0, 0);
        acc[1][1] = __builtin_amdgcn_mfma_f32_16x16x32_bf16(a1, b1, acc[1][1], 0, 0, 0);
        acc[1][2] = __builtin_amdgcn_mfma_f32_16x16x32_bf16(a1, b2, acc[1][2], 0, 0, 0);
        acc[1][3] = __builtin_amdgcn_mfma_f32_16x16x32_bf16(a1, b3, acc[1][3], 0, 0, 0);
        __syncthreads();
    }

#pragma unroll
    for (int rt = 0; rt < 2; ++rt) {
#pragma unroll
        for (int r = 0; r < 4; ++r) {
            int row = bm + wv * 32 + rt * 16 + quad * 4 + r;
            if (row >= M) continue;
#pragma unroll
            for (int ct = 0; ct < 4; ++ct) {
                int col = bn + ct * 16 + row_in;
                if (col < Nc) C[(long)row * Nc + col] = acc[rt][ct][r];
            }
        }
    }
}

// ---------------- per-(node,head) attention scores (float4) ----------------

__global__ void k_sd(const float* __restrict__ h, const float* __restrict__ a_src,
                     const float* __restrict__ a_dst, float* __restrict__ s,
                     float* __restrict__ d, int NH, int H, int C4) {
    int idx = blockIdx.x * blockDim.x + threadIdx.x;
    if (idx >= NH) return;
    int hh = idx % H;
    const float4* hp  = (const float4*)(h + (size_t)idx * C4 * 4);
    const float4* asp = (const float4*)(a_src + (size_t)hh * C4 * 4);
    const float4* adp = (const float4*)(a_dst + (size_t)hh * C4 * 4);
    float ss = 0.f, dd = 0.f;
    for (int c = 0; c < C4; ++c) {
        float4 hv = hp[c], av = asp[c], bv = adp[c];
        ss += hv.x * av.x + hv.y * av.y + hv.z * av.z + hv.w * av.w;
        dd += hv.x * bv.x + hv.y * bv.y + hv.z * bv.z + hv.w * bv.w;
    }
    s[idx] = ss;
    d[idx] = dd;
}

// ---------------- attention weights: one thread per (node, head) ----------------

__global__ void k_alpha(const float* __restrict__ s, const float* __restrict__ dsc,
                        const int* __restrict__ offs, const int* __restrict__ adj,
                        float* __restrict__ alpha, float* __restrict__ denom,
                        int NH, int H, int ET) {
    int idx = blockIdx.x * blockDim.x + threadIdx.x;
    if (idx >= NH) return;
    int hh = idx % H;
    int n  = idx / H;
    int beg = offs[n], end = offs[n + 1];
    float dn = dsc[idx];
    float m = -1e30f;
    for (int j = beg; j < end; ++j) {
        float e = s[adj[j] * H + hh] + dn;
        e = e > 0.f ? e : LRELU_SLOPE * e;
        m = fmaxf(m, e);
    }
    float dsum = 0.f;
    float* ap = alpha + (size_t)hh * ET;
    for (int j = beg; j < end; ++j) {
        float e = s[adj[j] * H + hh] + dn;
        e = e > 0.f ? e : LRELU_SLOPE * e;
        float w = expf(e - m);
        dsum += w;
        ap[j] = w;
    }
    denom[idx] = dsum;
}

// ---------------- aggregate: one thread per (node, head, c/4), single pass ----------------

__global__ void k_agg(const float* __restrict__ h, const float* __restrict__ alpha,
                      const float* __restrict__ denom, const int* __restrict__ offs,
                      const int* __restrict__ adj, const float* __restrict__ bias,
                      float* __restrict__ out, int N, int H, int C4, int ET, int act) {
    long tid = (long)blockIdx.x * blockDim.x + threadIdx.x;
    int HC4 = H * C4;
    if (tid >= (long)N * HC4) return;
    int c4 = (int)(tid % C4);
    int hh = (int)((tid / C4) % H);
    int n  = (int)(tid / HC4);
    int beg = offs[n], end = offs[n + 1];
    const float* ap = alpha + (size_t)hh * ET;
    int HC = HC4 * 4;
    float4 acc = {0.f, 0.f, 0.f, 0.f};
    for (int j = beg; j < end; ++j) {
        int sn = adj[j];
        float w = ap[j];
        float4 hv = *(const float4*)(h + (size_t)sn * HC + hh * C4 * 4 + c4 * 4);
        acc.x += w * hv.x; acc.y += w * hv.y; acc.z += w * hv.z; acc.w += w * hv.w;
    }
    float inv = 1.0f / denom[n * H + hh];
    float4 bv = *(const float4*)(bias + hh * C4 * 4 + c4 * 4);
    float4 o;
    o.x = acc.x * inv + bv.x;
    o.y = acc.y * inv + bv.y;
    o.z = acc.z * inv + bv.z;
    o.w = acc.w * inv + bv.w;
    if (act == 1) {
        o.x = o.x > 0.f ? o.x : (expf(o.x) - 1.f);
        o.y = o.y > 0.f ? o.y : (expf(o.y) - 1.f);
        o.z = o.z > 0.f ? o.z : (expf(o.z) - 1.f);
        o.w = o.w > 0.f ? o.w : (expf(o.w) - 1.f);
    }
    *(float4*)(out + tid * 4) = o;
}

// ---------------- fallback fused gather ----------------

__global__ void k_gather(const float* __restrict__ h, const float* __restrict__ s,
                         const float* __restrict__ dsc, const int* __restrict__ offs,
                         const int* __restrict__ adj, const float* __restrict__ bias,
                         float* __restrict__ out, int N, int H, int C, int act) {
    long tid = (long)blockIdx.x * blockDim.x + threadIdx.x;
    int HC = H * C;
    if (tid >= (long)N * HC) return;
    int c  = (int)(tid % C);
    int hh = (int)((tid / C) % H);
    int n  = (int)(tid / HC);
    int beg = offs[n], end = offs[n + 1];
    float dn = dsc[n * H + hh];
    float m = -1e30f;
    for (int j = beg; j < end; ++j) {
        int sn = adj[j];
        float e = s[sn * H + hh] + dn;
        e = e > 0.f ? e : LRELU_SLOPE * e;
        m = fmaxf(m, e);
    }
    float denom = 0.f, acc = 0.f;
    for (int j = beg; j < end; ++j) {
        int sn = adj[j];
        float e = s[sn * H + hh] + dn;
        e = e > 0.f ? e : LRELU_SLOPE * e;
        float w = expf(e - m);
        denom += w;
        acc += w * h[(long)sn * HC + hh * C + c];
    }
    float o = acc / denom + bias[hh * C + c];
    if (act == 1) o = o > 0.f ? o : (expf(o) - 1.f);
    out[tid] = o;
}

// ---------------- final log_softmax over C channels ----------------

__global__ void k_lsm(const float* __restrict__ in, float* __restrict__ out, int N, int C) {
    int n = blockIdx.x * blockDim.x + threadIdx.x;
    if (n >= N) return;
    long base = (long)n * C;
    float m = -1e30f;
    for (int c = 0; c < C; ++c) m = fmaxf(m, in[base + c]);
    float ssum = 0.f;
    for (int c = 0; c < C; ++c) ssum += expf(in[base + c] - m);
    float lse = m + logf(ssum);
    for (int c = 0; c < C; ++c) out[base + c] = in[base + c] - lse;
}

// ---------------- host ----------------

static inline size_t align_up(size_t x) { return (x + 255) & ~(size_t)255; }

extern "C" void kernel_launch(void* const* d_in, const int* in_sizes, int n_in,
                              void* d_out, int out_size, void* d_ws, size_t ws_size,
                              hipStream_t stream) {
    const float* x   = (const float*)d_in[0];
    const int*   ei  = (const int*)d_in[1];

    const int N = in_sizes[0] / 256;   // 50000
    const int E = in_sizes[1] / 2;     // 400000
    const int ET = E + N;
    const int NB = (N + 1023) / 1024;  // scan blocks

    size_t off = 0;
    char* ws = (char*)d_ws;
    auto take = [&](size_t bytes) { char* p = ws + off; off += align_up(bytes); return p; };
    int*   offs  = (int*)take((size_t)(N + 1) * 4);
    int*   wp    = (int*)take((size_t)N * 4);
    int*   adj   = (int*)take((size_t)ET * 4);
    int*   bsum  = (int*)take((size_t)(NB + 1) * 4);
    int*   bpre  = (int*)take((size_t)(NB + 1) * 4);
    float* sbuf  = (float*)take((size_t)N * 8 * 4);
    float* dbuf  = (float*)take((size_t)N * 8 * 4);
    float* dnbuf = (float*)take((size_t)N * 8 * 4);
    float* bufA  = (float*)take((size_t)N * 256 * 4);
    float* bufB  = (float*)take((size_t)N * 256 * 4);
    unsigned short* Abf = (unsigned short*)take((size_t)N * 256 * 2);
    unsigned short* WTb = (unsigned short*)take((size_t)256 * 256 * 2);
    size_t alpha_need = (size_t)ET * 8 * 4;
    bool use_split = (off + align_up(alpha_need)) <= ws_size;
    float* alpha = use_split ? (float*)take(alpha_need) : nullptr;

    // ---- CSR build ----
    hipMemsetAsync(wp, 0, (size_t)N * 4, stream);
    {
        int nb = (ET + 255) / 256;
        k_count<<<nb, 256, 0, stream>>>(ei, wp, E, N);
        k_scan_blk<<<NB, 1024, 0, stream>>>(wp, offs, bsum, N);
        k_scan<<<1, 1024, 0, stream>>>(bsum, bpre, NB);      // tiny: 1 iter
        k_scan_add<<<(N + 256) / 256, 256, 0, stream>>>(offs, bpre, wp, N, NB);
        k_scatter<<<nb, 256, 0, stream>>>(ei, wp, adj, E, N);
    }

    struct Layer { const float* W; const float* as; const float* ad; const float* b;
                   int Fin; int H; int C; };
    Layer layers[4] = {
        {(const float*)d_in[2],  (const float*)d_in[3],  (const float*)d_in[4],  (const float*)d_in[5],  256, 8, 32},
        {(const float*)d_in[6],  (const float*)d_in[7],  (const float*)d_in[8],  (const float*)d_in[9],  256, 4, 32},
        {(const float*)d_in[10], (const float*)d_in[11], (const float*)d_in[12], (const float*)d_in[13], 128, 2, 32},
        {(const float*)d_in[14], (const float*)d_in[15], (const float*)d_in[16], (const float*)d_in[17],  64, 1, 32},
    };

    const float* cur_x = x;
    float* hbuf = bufA;
    float* obuf = bufB;
    for (int li = 0; li < 4; ++li) {
        Layer& L = layers[li];
        int HC = L.H * L.C;
        int K = L.Fin;
        int act = (li < 3) ? 1 : 0;

        {
            long n4 = (long)N * K / 4;
            int nb = (int)((n4 + 255) / 256);
            k_cast<<<nb, 256, 0, stream>>>(cur_x, Abf, n4);
        }
        {
            int tot = K * HC;
            k_castWT<<<(tot + 255) / 256, 256, 0, stream>>>(L.W, WTb, K, HC);
        }
        {
            dim3 grd((HC + 63) / 64, (N + 127) / 128);
            k_mgemm<<<grd, 256, 0, stream>>>(Abf, WTb, hbuf, N, HC, K);
        }
        {
            int NH = N * L.H;
            k_sd<<<(NH + 255) / 256, 256, 0, stream>>>(hbuf, L.as, L.ad, sbuf, dbuf,
                                                       NH, L.H, L.C / 4);
        }
        if (use_split) {
            int NH = N * L.H;
            k_alpha<<<(NH + 255) / 256, 256, 0, stream>>>(sbuf, dbuf, offs, adj,
                                                          alpha, dnbuf, NH, L.H, ET);
            long total = (long)N * L.H * (L.C / 4);
            int nb = (int)((total + 255) / 256);
            k_agg<<<nb, 256, 0, stream>>>(hbuf, alpha, dnbuf, offs, adj, L.b, obuf,
                                          N, L.H, L.C / 4, ET, act);
        } else {
            long total = (long)N * HC;
            int nb = (int)((total + 255) / 256);
            k_gather<<<nb, 256, 0, stream>>>(hbuf, sbuf, dbuf, offs, adj, L.b, obuf,
                                             N, L.H, L.C, act);
        }
        cur_x = obuf;
        float* t = hbuf; hbuf = obuf; obuf = t;
    }

    k_lsm<<<(N + 255) / 256, 256, 0, stream>>>(cur_x, (float*)d_out, N, 32);
}

// Round 5
// 473.980 us; speedup vs baseline: 2.6181x; 1.1897x over previous
//
#include <hip/hip_runtime.h>
#include <hip/hip_bf16.h>

#define LRELU_SLOPE 0.2f

typedef __attribute__((ext_vector_type(8))) short short8;
typedef __attribute__((ext_vector_type(4))) float f32x4;

__device__ __forceinline__ unsigned short bf16r(float f) {
    unsigned int u = __builtin_bit_cast(unsigned int, f);
    u += 0x7fffu + ((u >> 16) & 1u);   // RNE
    return (unsigned short)(u >> 16);
}
__device__ __forceinline__ float bf2f(unsigned short u) {
    return __builtin_bit_cast(float, (unsigned int)u << 16);
}

// ---------------- CSR build ----------------

__global__ void k_count(const int* __restrict__ ei, int* __restrict__ cnt, int E, int N) {
    int e = blockIdx.x * blockDim.x + threadIdx.x;
    if (e >= E + N) return;
    int dst = (e < E) ? ei[E + e] : (e - E);
    atomicAdd(&cnt[dst], 1);
}

__global__ void k_scan_blk(const int* __restrict__ cnt, int* __restrict__ offs,
                           int* __restrict__ bsum, int N) {
    __shared__ int temp[1024];
    int t = threadIdx.x;
    int gi = blockIdx.x * 1024 + t;
    int v = (gi < N) ? cnt[gi] : 0;
    temp[t] = v;
    __syncthreads();
    for (int o = 1; o < 1024; o <<= 1) {
        int x = (t >= o) ? temp[t - o] : 0;
        __syncthreads();
        temp[t] += x;
        __syncthreads();
    }
    if (gi < N) offs[gi] = temp[t] - v;
    if (t == 1023) bsum[blockIdx.x] = temp[1023];
}

__global__ void k_scan(const int* __restrict__ cnt, int* __restrict__ offs, int N) {
    __shared__ int temp[1024];
    __shared__ int carry_s;
    int t = threadIdx.x;
    if (t == 0) carry_s = 0;
    __syncthreads();
    for (int base = 0; base < N; base += 1024) {
        int v = (base + t < N) ? cnt[base + t] : 0;
        temp[t] = v;
        __syncthreads();
        for (int o = 1; o < 1024; o <<= 1) {
            int x = (t >= o) ? temp[t - o] : 0;
            __syncthreads();
            temp[t] += x;
            __syncthreads();
        }
        int incl = temp[t];
        int carry = carry_s;
        if (base + t < N) offs[base + t] = carry + incl - v;
        __syncthreads();
        if (t == 1023) carry_s = carry + temp[1023];
        __syncthreads();
    }
    if (t == 0) offs[N] = carry_s;
}

__global__ void k_scan_add(int* __restrict__ offs, const int* __restrict__ bpre,
                           int* __restrict__ wp, int N, int nb) {
    int gi = blockIdx.x * blockDim.x + threadIdx.x;
    if (gi < N) {
        int v = offs[gi] + bpre[gi >> 10];
        offs[gi] = v;
        wp[gi] = v;
    } else if (gi == N) {
        offs[N] = bpre[nb];
    }
}

__global__ void k_scatter(const int* __restrict__ ei, int* __restrict__ wp,
                          int* __restrict__ adj, int E, int N) {
    int e = blockIdx.x * blockDim.x + threadIdx.x;
    if (e >= E + N) return;
    int srcn = (e < E) ? ei[e] : (e - E);
    int dst  = (e < E) ? ei[E + e] : (e - E);
    int pos = atomicAdd(&wp[dst], 1);
    adj[pos] = srcn;
}

// ---------------- casts ----------------

__global__ void k_cast(const float* __restrict__ in, unsigned short* __restrict__ out, long n4) {
    long i = (long)blockIdx.x * blockDim.x + threadIdx.x;
    if (i >= n4) return;
    float4 v = ((const float4*)in)[i];
    ushort4 o;
    o.x = bf16r(v.x); o.y = bf16r(v.y); o.z = bf16r(v.z); o.w = bf16r(v.w);
    ((ushort4*)out)[i] = o;
}

// WT[n*K + k] = bf16(W[k*Nc + n])
__global__ void k_castWT(const float* __restrict__ W, unsigned short* __restrict__ WT,
                         int K, int Nc) {
    int id = blockIdx.x * blockDim.x + threadIdx.x;
    if (id >= K * Nc) return;
    int n = id / K, k = id % K;
    WT[id] = bf16r(W[(long)k * Nc + n]);
}

// ---------------- MFMA GEMM: Cb16[M,Nc](bf16) = A[M,K](bf16) * WT[Nc,K]^T ----------------

#define PSTR 40  // padded LDS row stride in shorts

__global__ __launch_bounds__(256) void k_mgemm(const unsigned short* __restrict__ A,
                                               const unsigned short* __restrict__ WT,
                                               unsigned short* __restrict__ Cb,
                                               int M, int Nc, int K) {
    __shared__ __align__(16) unsigned short As[128 * PSTR];
    __shared__ __align__(16) unsigned short Bs[64 * PSTR];
    int t = threadIdx.x;
    int wv = t >> 6, l = t & 63;
    int bm = blockIdx.y * 128, bn = blockIdx.x * 64;

    f32x4 acc[2][4];
#pragma unroll
    for (int i = 0; i < 2; ++i)
#pragma unroll
        for (int j = 0; j < 4; ++j) acc[i][j] = (f32x4){0.f, 0.f, 0.f, 0.f};

    int ar0 = t >> 2, akc0 = t & 3;
    int ar1 = (t + 256) >> 2, akc1 = t & 3;
    int bc0 = t >> 2, bkc0 = t & 3;
    int grA0 = min(bm + ar0, M - 1);
    int grA1 = min(bm + ar1, M - 1);
    int gcB0 = min(bn + bc0, Nc - 1);

    int row_in = l & 15, quad = l >> 4;
    const short8* apf0 = (const short8*)&As[(wv * 32 + row_in) * PSTR + quad * 8];
    const short8* apf1 = (const short8*)&As[(wv * 32 + 16 + row_in) * PSTR + quad * 8];
    const short8* bpf0 = (const short8*)&Bs[(row_in) * PSTR + quad * 8];
    const short8* bpf1 = (const short8*)&Bs[(16 + row_in) * PSTR + quad * 8];
    const short8* bpf2 = (const short8*)&Bs[(32 + row_in) * PSTR + quad * 8];
    const short8* bpf3 = (const short8*)&Bs[(48 + row_in) * PSTR + quad * 8];

    for (int k0 = 0; k0 < K; k0 += 32) {
        *(short8*)&As[ar0 * PSTR + akc0 * 8] =
            *(const short8*)&A[(long)grA0 * K + k0 + akc0 * 8];
        *(short8*)&As[ar1 * PSTR + akc1 * 8] =
            *(const short8*)&A[(long)grA1 * K + k0 + akc1 * 8];
        *(short8*)&Bs[bc0 * PSTR + bkc0 * 8] =
            *(const short8*)&WT[(long)gcB0 * K + k0 + bkc0 * 8];
        __syncthreads();

        short8 a0 = *apf0, a1 = *apf1;
        short8 b0 = *bpf0, b1 = *bpf1, b2 = *bpf2, b3 = *bpf3;
        acc[0][0] = __builtin_amdgcn_mfma_f32_16x16x32_bf16(a0, b0, acc[0][0], 0, 0, 0);
        acc[0][1] = __builtin_amdgcn_mfma_f32_16x16x32_bf16(a0, b1, acc[0][1], 0, 0, 0);
        acc[0][2] = __builtin_amdgcn_mfma_f32_16x16x32_bf16(a0, b2, acc[0][2], 0, 0, 0);
        acc[0][3] = __builtin_amdgcn_mfma_f32_16x16x32_bf16(a0, b3, acc[0][3], 0, 0, 0);
        acc[1][0] = __builtin_amdgcn_mfma_f32_16x16x32_bf16(a1, b0, acc[1][0], 0, 0, 0);
        acc[1][1] = __builtin_amdgcn_mfma_f32_16x16x32_bf16(a1, b1, acc[1][1], 0, 0, 0);
        acc[1][2] = __builtin_amdgcn_mfma_f32_16x16x32_bf16(a1, b2, acc[1][2], 0, 0, 0);
        acc[1][3] = __builtin_amdgcn_mfma_f32_16x16x32_bf16(a1, b3, acc[1][3], 0, 0, 0);
        __syncthreads();
    }

    // epilogue: C/D layout col=lane&15, row=quad*4+reg; store bf16
#pragma unroll
    for (int rt = 0; rt < 2; ++rt) {
#pragma unroll
        for (int r = 0; r < 4; ++r) {
            int row = bm + wv * 32 + rt * 16 + quad * 4 + r;
            if (row >= M) continue;
#pragma unroll
            for (int ct = 0; ct < 4; ++ct) {
                int col = bn + ct * 16 + row_in;
                if (col < Nc) Cb[(long)row * Nc + col] = bf16r(acc[rt][ct][r]);
            }
        }
    }
}

// ---------------- per-(node,head) attention scores (bf16 h) ----------------

__global__ void k_sd(const unsigned short* __restrict__ h, const float* __restrict__ a_src,
                     const float* __restrict__ a_dst, float* __restrict__ s,
                     float* __restrict__ d, int NH, int H, int C) {
    int idx = blockIdx.x * blockDim.x + threadIdx.x;
    if (idx >= NH) return;
    int hh = idx % H;
    const unsigned short* hp = h + (size_t)idx * C;
    const float* asp = a_src + (size_t)hh * C;
    const float* adp = a_dst + (size_t)hh * C;
    float ss = 0.f, dd = 0.f;
    for (int c0 = 0; c0 < C; c0 += 8) {
        short8 hv = *(const short8*)(hp + c0);
#pragma unroll
        for (int u = 0; u < 8; ++u) {
            float v = bf2f((unsigned short)hv[u]);
            ss += v * asp[c0 + u];
            dd += v * adp[c0 + u];
        }
    }
    s[idx] = ss;
    d[idx] = dd;
}

// ---------------- attention weights: one thread per (node, head) ----------------

__global__ void k_alpha(const float* __restrict__ s, const float* __restrict__ dsc,
                        const int* __restrict__ offs, const int* __restrict__ adj,
                        float* __restrict__ alpha, float* __restrict__ denom,
                        int NH, int H, int ET) {
    int idx = blockIdx.x * blockDim.x + threadIdx.x;
    if (idx >= NH) return;
    int hh = idx % H;
    int n  = idx / H;
    int beg = offs[n], end = offs[n + 1];
    float dn = dsc[idx];
    float m = -1e30f;
    for (int j = beg; j < end; ++j) {
        float e = s[adj[j] * H + hh] + dn;
        e = e > 0.f ? e : LRELU_SLOPE * e;
        m = fmaxf(m, e);
    }
    float dsum = 0.f;
    float* ap = alpha + (size_t)hh * ET;
    for (int j = beg; j < end; ++j) {
        float e = s[adj[j] * H + hh] + dn;
        e = e > 0.f ? e : LRELU_SLOPE * e;
        float w = expf(e - m);
        dsum += w;
        ap[j] = w;
    }
    denom[idx] = dsum;
}

// ---------------- aggregate: one thread per (node, head, c/8), bf16 h ----------------
// act==1: out16 gets bf16(elu(o))  (next layer's GEMM input, identical to old cast chain)
// act==0: out32 gets fp32 o        (final layer, feeds log_softmax)

__global__ void k_agg(const unsigned short* __restrict__ h, const float* __restrict__ alpha,
                      const float* __restrict__ denom, const int* __restrict__ offs,
                      const int* __restrict__ adj, const float* __restrict__ bias,
                      unsigned short* __restrict__ out16, float* __restrict__ out32,
                      int N, int H, int C8, int ET, int act) {
    long tid = (long)blockIdx.x * blockDim.x + threadIdx.x;
    int HC8 = H * C8;
    if (tid >= (long)N * HC8) return;
    int c8 = (int)(tid % C8);
    int hh = (int)((tid / C8) % H);
    int n  = (int)(tid / HC8);
    int beg = offs[n], end = offs[n + 1];
    const float* ap = alpha + (size_t)hh * ET;
    int HC = HC8 * 8;
    int coff = hh * C8 * 8 + c8 * 8;
    float acc[8];
#pragma unroll
    for (int u = 0; u < 8; ++u) acc[u] = 0.f;
    for (int j = beg; j < end; ++j) {
        int sn = adj[j];
        float w = ap[j];
        short8 hv = *(const short8*)(h + (size_t)sn * HC + coff);
#pragma unroll
        for (int u = 0; u < 8; ++u) acc[u] += w * bf2f((unsigned short)hv[u]);
    }
    float inv = 1.0f / denom[n * H + hh];
    float o[8];
#pragma unroll
    for (int u = 0; u < 8; ++u) o[u] = acc[u] * inv + bias[coff + u];
    if (act == 1) {
        short8 pk;
#pragma unroll
        for (int u = 0; u < 8; ++u) {
            float v = o[u] > 0.f ? o[u] : (expf(o[u]) - 1.f);
            pk[u] = (short)bf16r(v);
        }
        *(short8*)(out16 + tid * 8) = pk;
    } else {
        float4 lo = {o[0], o[1], o[2], o[3]};
        float4 hi = {o[4], o[5], o[6], o[7]};
        *(float4*)(out32 + tid * 8) = lo;
        *(float4*)(out32 + tid * 8 + 4) = hi;
    }
}

// ---------------- final log_softmax over C channels ----------------

__global__ void k_lsm(const float* __restrict__ in, float* __restrict__ out, int N, int C) {
    int n = blockIdx.x * blockDim.x + threadIdx.x;
    if (n >= N) return;
    long base = (long)n * C;
    float m = -1e30f;
    for (int c = 0; c < C; ++c) m = fmaxf(m, in[base + c]);
    float ssum = 0.f;
    for (int c = 0; c < C; ++c) ssum += expf(in[base + c] - m);
    float lse = m + logf(ssum);
    for (int c = 0; c < C; ++c) out[base + c] = in[base + c] - lse;
}

// ---------------- host ----------------

static inline size_t align_up(size_t x) { return (x + 255) & ~(size_t)255; }

extern "C" void kernel_launch(void* const* d_in, const int* in_sizes, int n_in,
                              void* d_out, int out_size, void* d_ws, size_t ws_size,
                              hipStream_t stream) {
    const float* x   = (const float*)d_in[0];
    const int*   ei  = (const int*)d_in[1];

    const int N = in_sizes[0] / 256;   // 50000
    const int E = in_sizes[1] / 2;     // 400000
    const int ET = E + N;
    const int NB = (N + 1023) / 1024;

    size_t off = 0;
    char* ws = (char*)d_ws;
    auto take = [&](size_t bytes) { char* p = ws + off; off += align_up(bytes); return p; };
    int*   offs  = (int*)take((size_t)(N + 1) * 4);
    int*   wp    = (int*)take((size_t)N * 4);
    int*   adj   = (int*)take((size_t)ET * 4);
    int*   bsum  = (int*)take((size_t)(NB + 1) * 4);
    int*   bpre  = (int*)take((size_t)(NB + 1) * 4);
    float* sbuf  = (float*)take((size_t)N * 8 * 4);
    float* dbuf  = (float*)take((size_t)N * 8 * 4);
    float* dnbuf = (float*)take((size_t)N * 8 * 4);
    unsigned short* Xb = (unsigned short*)take((size_t)N * 256 * 2);  // GEMM input
    unsigned short* Yb = (unsigned short*)take((size_t)N * 256 * 2);  // h (GEMM out)
    float* fbuf  = (float*)take((size_t)N * 32 * 4);                  // final fp32 out
    unsigned short* WTb = (unsigned short*)take((size_t)256 * 256 * 2);
    float* alpha = (float*)take((size_t)ET * 8 * 4);
    (void)ws_size;

    // ---- CSR build ----
    hipMemsetAsync(wp, 0, (size_t)N * 4, stream);
    {
        int nb = (ET + 255) / 256;
        k_count<<<nb, 256, 0, stream>>>(ei, wp, E, N);
        k_scan_blk<<<NB, 1024, 0, stream>>>(wp, offs, bsum, N);
        k_scan<<<1, 1024, 0, stream>>>(bsum, bpre, NB);
        k_scan_add<<<(N + 256) / 256, 256, 0, stream>>>(offs, bpre, wp, N, NB);
        k_scatter<<<nb, 256, 0, stream>>>(ei, wp, adj, E, N);
    }

    struct Layer { const float* W; const float* as; const float* ad; const float* b;
                   int Fin; int H; int C; };
    Layer layers[4] = {
        {(const float*)d_in[2],  (const float*)d_in[3],  (const float*)d_in[4],  (const float*)d_in[5],  256, 8, 32},
        {(const float*)d_in[6],  (const float*)d_in[7],  (const float*)d_in[8],  (const float*)d_in[9],  256, 4, 32},
        {(const float*)d_in[10], (const float*)d_in[11], (const float*)d_in[12], (const float*)d_in[13], 128, 2, 32},
        {(const float*)d_in[14], (const float*)d_in[15], (const float*)d_in[16], (const float*)d_in[17],  64, 1, 32},
    };

    // layer-0 input: cast x to bf16 into Xb
    {
        long n4 = (long)N * 256 / 4;
        int nb = (int)((n4 + 255) / 256);
        k_cast<<<nb, 256, 0, stream>>>(x, Xb, n4);
    }

    for (int li = 0; li < 4; ++li) {
        Layer& L = layers[li];
        int HC = L.H * L.C;
        int K = L.Fin;
        int act = (li < 3) ? 1 : 0;

        {
            int tot = K * HC;
            k_castWT<<<(tot + 255) / 256, 256, 0, stream>>>(L.W, WTb, K, HC);
        }
        {
            dim3 grd((HC + 63) / 64, (N + 127) / 128);
            k_mgemm<<<grd, 256, 0, stream>>>(Xb, WTb, Yb, N, HC, K);
        }
        {
            int NH = N * L.H;
            k_sd<<<(NH + 255) / 256, 256, 0, stream>>>(Yb, L.as, L.ad, sbuf, dbuf,
                                                       NH, L.H, L.C);
        }
        {
            int NH = N * L.H;
            k_alpha<<<(NH + 255) / 256, 256, 0, stream>>>(sbuf, dbuf, offs, adj,
                                                          alpha, dnbuf, NH, L.H, ET);
        }
        {
            long total = (long)N * L.H * (L.C / 8);
            int nb = (int)((total + 255) / 256);
            // act: bf16 out into Xb (next GEMM input). final: fp32 into fbuf.
            k_agg<<<nb, 256, 0, stream>>>(Yb, alpha, dnbuf, offs, adj, L.b,
                                          Xb, fbuf, N, L.H, L.C / 8, ET, act);
        }
    }

    k_lsm<<<(N + 255) / 256, 256, 0, stream>>>(fbuf, (float*)d_out, N, 32);
}

// Round 6
// 392.102 us; speedup vs baseline: 3.1648x; 1.2088x over previous
//
#include <hip/hip_runtime.h>
#include <hip/hip_bf16.h>

#define LRELU_SLOPE 0.2f

typedef __attribute__((ext_vector_type(8))) short short8;
typedef __attribute__((ext_vector_type(4))) float f32x4;

__device__ __forceinline__ unsigned short bf16r(float f) {
    unsigned int u = __builtin_bit_cast(unsigned int, f);
    u += 0x7fffu + ((u >> 16) & 1u);   // RNE
    return (unsigned short)(u >> 16);
}
__device__ __forceinline__ float bf2f(unsigned short u) {
    return __builtin_bit_cast(float, (unsigned int)u << 16);
}

// ---------------- CSR build ----------------

__global__ void k_count(const int* __restrict__ ei, int* __restrict__ cnt, int E, int N) {
    int e = blockIdx.x * blockDim.x + threadIdx.x;
    if (e >= E + N) return;
    int dst = (e < E) ? ei[E + e] : (e - E);
    atomicAdd(&cnt[dst], 1);
}

__global__ void k_scan_blk(const int* __restrict__ cnt, int* __restrict__ offs,
                           int* __restrict__ bsum, int N) {
    __shared__ int temp[1024];
    int t = threadIdx.x;
    int gi = blockIdx.x * 1024 + t;
    int v = (gi < N) ? cnt[gi] : 0;
    temp[t] = v;
    __syncthreads();
    for (int o = 1; o < 1024; o <<= 1) {
        int x = (t >= o) ? temp[t - o] : 0;
        __syncthreads();
        temp[t] += x;
        __syncthreads();
    }
    if (gi < N) offs[gi] = temp[t] - v;
    if (t == 1023) bsum[blockIdx.x] = temp[1023];
}

__global__ void k_scan(const int* __restrict__ cnt, int* __restrict__ offs, int N) {
    __shared__ int temp[1024];
    __shared__ int carry_s;
    int t = threadIdx.x;
    if (t == 0) carry_s = 0;
    __syncthreads();
    for (int base = 0; base < N; base += 1024) {
        int v = (base + t < N) ? cnt[base + t] : 0;
        temp[t] = v;
        __syncthreads();
        for (int o = 1; o < 1024; o <<= 1) {
            int x = (t >= o) ? temp[t - o] : 0;
            __syncthreads();
            temp[t] += x;
            __syncthreads();
        }
        int incl = temp[t];
        int carry = carry_s;
        if (base + t < N) offs[base + t] = carry + incl - v;
        __syncthreads();
        if (t == 1023) carry_s = carry + temp[1023];
        __syncthreads();
    }
    if (t == 0) offs[N] = carry_s;
}

__global__ void k_scan_add(int* __restrict__ offs, const int* __restrict__ bpre,
                           int* __restrict__ wp, int N, int nb) {
    int gi = blockIdx.x * blockDim.x + threadIdx.x;
    if (gi < N) {
        int v = offs[gi] + bpre[gi >> 10];
        offs[gi] = v;
        wp[gi] = v;
    } else if (gi == N) {
        offs[N] = bpre[nb];
    }
}

__global__ void k_scatter(const int* __restrict__ ei, int* __restrict__ wp,
                          int* __restrict__ adj, int E, int N) {
    int e = blockIdx.x * blockDim.x + threadIdx.x;
    if (e >= E + N) return;
    int srcn = (e < E) ? ei[e] : (e - E);
    int dst  = (e < E) ? ei[E + e] : (e - E);
    int pos = atomicAdd(&wp[dst], 1);
    adj[pos] = srcn;
}

// ---------------- casts ----------------

__global__ void k_cast(const float* __restrict__ in, unsigned short* __restrict__ out, long n4) {
    long i = (long)blockIdx.x * blockDim.x + threadIdx.x;
    if (i >= n4) return;
    float4 v = ((const float4*)in)[i];
    ushort4 o;
    o.x = bf16r(v.x); o.y = bf16r(v.y); o.z = bf16r(v.z); o.w = bf16r(v.w);
    ((ushort4*)out)[i] = o;
}

// all 4 layers' W -> WT (bf16, transposed) in one dispatch
__global__ void k_castWT4(const float* __restrict__ Wa, const float* __restrict__ Wb,
                          const float* __restrict__ Wc, const float* __restrict__ Wd,
                          unsigned short* __restrict__ Ta, unsigned short* __restrict__ Tb,
                          unsigned short* __restrict__ Tc, unsigned short* __restrict__ Td) {
    int id = blockIdx.x * blockDim.x + threadIdx.x;
    const float* W; unsigned short* T; int K, Nc;
    if (id < 65536)       { W = Wa; T = Ta; K = 256; Nc = 256; }
    else if (id < 98304)  { id -= 65536;  W = Wb; T = Tb; K = 256; Nc = 128; }
    else if (id < 106496) { id -= 98304;  W = Wc; T = Tc; K = 128; Nc = 64; }
    else if (id < 108544) { id -= 106496; W = Wd; T = Td; K = 64;  Nc = 32; }
    else return;
    int n = id / K, k = id % K;
    T[id] = bf16r(W[(long)k * Nc + n]);
}

// ---------------- MFMA GEMM: Cb16[M,Nc](bf16) = A[M,K](bf16) * WT[Nc,K]^T ----------------

#define PSTR 40  // padded LDS row stride in shorts

__global__ __launch_bounds__(256) void k_mgemm(const unsigned short* __restrict__ A,
                                               const unsigned short* __restrict__ WT,
                                               unsigned short* __restrict__ Cb,
                                               int M, int Nc, int K) {
    __shared__ __align__(16) unsigned short As[128 * PSTR];
    __shared__ __align__(16) unsigned short Bs[64 * PSTR];
    int t = threadIdx.x;
    int wv = t >> 6, l = t & 63;
    int bm = blockIdx.y * 128, bn = blockIdx.x * 64;

    f32x4 acc[2][4];
#pragma unroll
    for (int i = 0; i < 2; ++i)
#pragma unroll
        for (int j = 0; j < 4; ++j) acc[i][j] = (f32x4){0.f, 0.f, 0.f, 0.f};

    int ar0 = t >> 2, akc0 = t & 3;
    int ar1 = (t + 256) >> 2, akc1 = t & 3;
    int bc0 = t >> 2, bkc0 = t & 3;
    int grA0 = min(bm + ar0, M - 1);
    int grA1 = min(bm + ar1, M - 1);
    int gcB0 = min(bn + bc0, Nc - 1);

    int row_in = l & 15, quad = l >> 4;
    const short8* apf0 = (const short8*)&As[(wv * 32 + row_in) * PSTR + quad * 8];
    const short8* apf1 = (const short8*)&As[(wv * 32 + 16 + row_in) * PSTR + quad * 8];
    const short8* bpf0 = (const short8*)&Bs[(row_in) * PSTR + quad * 8];
    const short8* bpf1 = (const short8*)&Bs[(16 + row_in) * PSTR + quad * 8];
    const short8* bpf2 = (const short8*)&Bs[(32 + row_in) * PSTR + quad * 8];
    const short8* bpf3 = (const short8*)&Bs[(48 + row_in) * PSTR + quad * 8];

    for (int k0 = 0; k0 < K; k0 += 32) {
        *(short8*)&As[ar0 * PSTR + akc0 * 8] =
            *(const short8*)&A[(long)grA0 * K + k0 + akc0 * 8];
        *(short8*)&As[ar1 * PSTR + akc1 * 8] =
            *(const short8*)&A[(long)grA1 * K + k0 + akc1 * 8];
        *(short8*)&Bs[bc0 * PSTR + bkc0 * 8] =
            *(const short8*)&WT[(long)gcB0 * K + k0 + bkc0 * 8];
        __syncthreads();

        short8 a0 = *apf0, a1 = *apf1;
        short8 b0 = *bpf0, b1 = *bpf1, b2 = *bpf2, b3 = *bpf3;
        acc[0][0] = __builtin_amdgcn_mfma_f32_16x16x32_bf16(a0, b0, acc[0][0], 0, 0, 0);
        acc[0][1] = __builtin_amdgcn_mfma_f32_16x16x32_bf16(a0, b1, acc[0][1], 0, 0, 0);
        acc[0][2] = __builtin_amdgcn_mfma_f32_16x16x32_bf16(a0, b2, acc[0][2], 0, 0, 0);
        acc[0][3] = __builtin_amdgcn_mfma_f32_16x16x32_bf16(a0, b3, acc[0][3], 0, 0, 0);
        acc[1][0] = __builtin_amdgcn_mfma_f32_16x16x32_bf16(a1, b0, acc[1][0], 0, 0, 0);
        acc[1][1] = __builtin_amdgcn_mfma_f32_16x16x32_bf16(a1, b1, acc[1][1], 0, 0, 0);
        acc[1][2] = __builtin_amdgcn_mfma_f32_16x16x32_bf16(a1, b2, acc[1][2], 0, 0, 0);
        acc[1][3] = __builtin_amdgcn_mfma_f32_16x16x32_bf16(a1, b3, acc[1][3], 0, 0, 0);
        __syncthreads();
    }

    // epilogue: C/D layout col=lane&15, row=quad*4+reg; store bf16
#pragma unroll
    for (int rt = 0; rt < 2; ++rt) {
#pragma unroll
        for (int r = 0; r < 4; ++r) {
            int row = bm + wv * 32 + rt * 16 + quad * 4 + r;
            if (row >= M) continue;
#pragma unroll
            for (int ct = 0; ct < 4; ++ct) {
                int col = bn + ct * 16 + row_in;
                if (col < Nc) Cb[(long)row * Nc + col] = bf16r(acc[rt][ct][r]);
            }
        }
    }
}

// ---------------- per-(node,head) attention scores (bf16 h) ----------------

__global__ void k_sd(const unsigned short* __restrict__ h, const float* __restrict__ a_src,
                     const float* __restrict__ a_dst, float* __restrict__ s,
                     float* __restrict__ d, int NH, int H, int C) {
    int idx = blockIdx.x * blockDim.x + threadIdx.x;
    if (idx >= NH) return;
    int hh = idx % H;
    const unsigned short* hp = h + (size_t)idx * C;
    const float* asp = a_src + (size_t)hh * C;
    const float* adp = a_dst + (size_t)hh * C;
    float ss = 0.f, dd = 0.f;
    for (int c0 = 0; c0 < C; c0 += 8) {
        short8 hv = *(const short8*)(hp + c0);
#pragma unroll
        for (int u = 0; u < 8; ++u) {
            float v = bf2f((unsigned short)hv[u]);
            ss += v * asp[c0 + u];
            dd += v * adp[c0 + u];
        }
    }
    s[idx] = ss;
    d[idx] = dd;
}

// ---------------- fused online-softmax aggregate ----------------
// one thread per (node, head, c/8); single pass over in-edges.
// s table is tiny (N*H*4B) -> L2-resident; recompute e per thread instead of an
// alpha round-trip through global (round-5 k_alpha eliminated).
// act==1: out16 = bf16(elu(o));  act==0: out32 = fp32 o (final layer).

__global__ void k_aggf(const unsigned short* __restrict__ h, const float* __restrict__ s,
                       const float* __restrict__ dsc, const int* __restrict__ offs,
                       const int* __restrict__ adj, const float* __restrict__ bias,
                       unsigned short* __restrict__ out16, float* __restrict__ out32,
                       int N, int H, int C8, int act) {
    long tid = (long)blockIdx.x * blockDim.x + threadIdx.x;
    int HC8 = H * C8;
    if (tid >= (long)N * HC8) return;
    int c8 = (int)(tid % C8);
    int hh = (int)((tid / C8) % H);
    int n  = (int)(tid / HC8);
    int beg = offs[n], end = offs[n + 1];
    float dn = dsc[n * H + hh];
    int HC = HC8 * 8;
    int coff = hh * C8 * 8 + c8 * 8;

    float m = -1e30f, denom = 0.f;
    float acc[8];
#pragma unroll
    for (int u = 0; u < 8; ++u) acc[u] = 0.f;

    for (int j = beg; j < end; ++j) {
        int sn = adj[j];
        float e = s[sn * H + hh] + dn;
        e = e > 0.f ? e : LRELU_SLOPE * e;
        float mn = fmaxf(m, e);
        float sc = __expf(m - mn);   // m=-1e30 initially -> sc=0, correct
        float w  = __expf(e - mn);
        m = mn;
        denom = denom * sc + w;
        short8 hv = *(const short8*)(h + (size_t)sn * HC + coff);
#pragma unroll
        for (int u = 0; u < 8; ++u)
            acc[u] = acc[u] * sc + w * bf2f((unsigned short)hv[u]);
    }

    float inv = 1.0f / denom;
    float o[8];
#pragma unroll
    for (int u = 0; u < 8; ++u) o[u] = acc[u] * inv + bias[coff + u];
    if (act == 1) {
        short8 pk;
#pragma unroll
        for (int u = 0; u < 8; ++u) {
            float v = o[u] > 0.f ? o[u] : (expf(o[u]) - 1.f);
            pk[u] = (short)bf16r(v);
        }
        *(short8*)(out16 + tid * 8) = pk;
    } else {
        float4 lo = {o[0], o[1], o[2], o[3]};
        float4 hi = {o[4], o[5], o[6], o[7]};
        *(float4*)(out32 + tid * 8) = lo;
        *(float4*)(out32 + tid * 8 + 4) = hi;
    }
}

// ---------------- final log_softmax over C channels ----------------

__global__ void k_lsm(const float* __restrict__ in, float* __restrict__ out, int N, int C) {
    int n = blockIdx.x * blockDim.x + threadIdx.x;
    if (n >= N) return;
    long base = (long)n * C;
    float m = -1e30f;
    for (int c = 0; c < C; ++c) m = fmaxf(m, in[base + c]);
    float ssum = 0.f;
    for (int c = 0; c < C; ++c) ssum += expf(in[base + c] - m);
    float lse = m + logf(ssum);
    for (int c = 0; c < C; ++c) out[base + c] = in[base + c] - lse;
}

// ---------------- host ----------------

static inline size_t align_up(size_t x) { return (x + 255) & ~(size_t)255; }

extern "C" void kernel_launch(void* const* d_in, const int* in_sizes, int n_in,
                              void* d_out, int out_size, void* d_ws, size_t ws_size,
                              hipStream_t stream) {
    const float* x   = (const float*)d_in[0];
    const int*   ei  = (const int*)d_in[1];

    const int N = in_sizes[0] / 256;   // 50000
    const int E = in_sizes[1] / 2;     // 400000
    const int ET = E + N;
    const int NB = (N + 1023) / 1024;

    size_t off = 0;
    char* ws = (char*)d_ws;
    auto take = [&](size_t bytes) { char* p = ws + off; off += align_up(bytes); return p; };
    int*   offs  = (int*)take((size_t)(N + 1) * 4);
    int*   wp    = (int*)take((size_t)N * 4);
    int*   adj   = (int*)take((size_t)ET * 4);
    int*   bsum  = (int*)take((size_t)(NB + 1) * 4);
    int*   bpre  = (int*)take((size_t)(NB + 1) * 4);
    float* sbuf  = (float*)take((size_t)N * 8 * 4);
    float* dbuf  = (float*)take((size_t)N * 8 * 4);
    unsigned short* Xb = (unsigned short*)take((size_t)N * 256 * 2);  // GEMM input
    unsigned short* Yb = (unsigned short*)take((size_t)N * 256 * 2);  // h (GEMM out)
    float* fbuf  = (float*)take((size_t)N * 32 * 4);                  // final fp32 out
    unsigned short* WT0 = (unsigned short*)take((size_t)256 * 256 * 2);
    unsigned short* WT1 = (unsigned short*)take((size_t)256 * 128 * 2);
    unsigned short* WT2 = (unsigned short*)take((size_t)128 * 64 * 2);
    unsigned short* WT3 = (unsigned short*)take((size_t)64 * 32 * 2);
    (void)ws_size;

    // ---- CSR build ----
    hipMemsetAsync(wp, 0, (size_t)N * 4, stream);
    {
        int nb = (ET + 255) / 256;
        k_count<<<nb, 256, 0, stream>>>(ei, wp, E, N);
        k_scan_blk<<<NB, 1024, 0, stream>>>(wp, offs, bsum, N);
        k_scan<<<1, 1024, 0, stream>>>(bsum, bpre, NB);
        k_scan_add<<<(N + 256) / 256, 256, 0, stream>>>(offs, bpre, wp, N, NB);
        k_scatter<<<nb, 256, 0, stream>>>(ei, wp, adj, E, N);
    }

    struct Layer { const float* as; const float* ad; const float* b;
                   const unsigned short* WT; int Fin; int H; int C; };
    Layer layers[4] = {
        {(const float*)d_in[3],  (const float*)d_in[4],  (const float*)d_in[5],  WT0, 256, 8, 32},
        {(const float*)d_in[7],  (const float*)d_in[8],  (const float*)d_in[9],  WT1, 256, 4, 32},
        {(const float*)d_in[11], (const float*)d_in[12], (const float*)d_in[13], WT2, 128, 2, 32},
        {(const float*)d_in[15], (const float*)d_in[16], (const float*)d_in[17], WT3,  64, 1, 32},
    };

    // all weights -> bf16 transposed, one dispatch
    k_castWT4<<<(108544 + 255) / 256, 256, 0, stream>>>(
        (const float*)d_in[2], (const float*)d_in[6], (const float*)d_in[10],
        (const float*)d_in[14], WT0, WT1, WT2, WT3);

    // layer-0 input: cast x to bf16
    {
        long n4 = (long)N * 256 / 4;
        k_cast<<<(int)((n4 + 255) / 256), 256, 0, stream>>>(x, Xb, n4);
    }

    for (int li = 0; li < 4; ++li) {
        Layer& L = layers[li];
        int HC = L.H * L.C;
        int K = L.Fin;
        int act = (li < 3) ? 1 : 0;

        {
            dim3 grd((HC + 63) / 64, (N + 127) / 128);
            k_mgemm<<<grd, 256, 0, stream>>>(Xb, L.WT, Yb, N, HC, K);
        }
        {
            int NH = N * L.H;
            k_sd<<<(NH + 255) / 256, 256, 0, stream>>>(Yb, L.as, L.ad, sbuf, dbuf,
                                                       NH, L.H, L.C);
        }
        {
            long total = (long)N * L.H * (L.C / 8);
            int nb = (int)((total + 255) / 256);
            k_aggf<<<nb, 256, 0, stream>>>(Yb, sbuf, dbuf, offs, adj, L.b,
                                           Xb, fbuf, N, L.H, L.C / 8, act);
        }
    }

    k_lsm<<<(N + 255) / 256, 256, 0, stream>>>(fbuf, (float*)d_out, N, 32);
}